// Round 22
// baseline (461.984 us; speedup 1.0000x reference)
//
#include <hip/hip_runtime.h>
#include <hip/hip_bf16.h>
#include <math.h>

#define B_ 4
#define N_ 4096
#define K_ 20
#define NK_ (N_*K_)   // 81920
#define G_ 16
#define EPS_ 1e-5f
#define NBLK_ (NK_/256)   // 320 column-blocks per batch

typedef __hip_bfloat16 bf16;
typedef short bf16x8v __attribute__((ext_vector_type(8)));
typedef unsigned short u16x8v __attribute__((ext_vector_type(8)));
typedef unsigned short u16x4v __attribute__((ext_vector_type(4)));
typedef float f32x4v __attribute__((ext_vector_type(4)));

__device__ inline float b2f(bf16 v) { return __bfloat162float(v); }
__device__ inline bf16  f2b(float v){ return __float2bfloat16(v); }
__device__ inline float us2f(unsigned short u){ unsigned int i = ((unsigned)u) << 16; float f; __builtin_memcpy(&f, &i, 4); return f; }
__device__ inline unsigned short f2us(float f){ bf16 h = __float2bfloat16(f); unsigned short u; __builtin_memcpy(&u, &h, 2); return u; }

template<int CTRL>
__device__ inline float dppmax_step(float v)
{
    int i; __builtin_memcpy(&i, &v, 4);
    int m = __builtin_amdgcn_update_dpp((int)0xFF800000, i, CTRL, 0xF, 0xF, false);
    float f; __builtin_memcpy(&f, &m, 4);
    return fmaxf(v, f);
}

// ---------------- ptsq prep: pack [x,y,z,xx] per point (xx bit-exact np formula) ----------------
__global__ __launch_bounds__(256) void ptsq_kernel(const float* __restrict__ pts, float* __restrict__ ptsq)
{
    int t = blockIdx.x * 256 + threadIdx.x;   // [0, B*N)
    int b = t >> 12, n = t & (N_ - 1);
    const float* pb = pts + (size_t)b * 6 * N_;
    float x = pb[n], y = pb[N_ + n], z = pb[2 * N_ + n];
    float xx = __fadd_rn(__fadd_rn(__fmul_rn(x, x), __fmul_rn(y, y)), __fmul_rn(z, z));
    f32x4v v = { x, y, z, xx };
    *reinterpret_cast<f32x4v*>(ptsq + (size_t)t * 4) = v;
}

// ---------------- kNN: one WAVE per (b,i); float4 candidates + two-level cache + DPP ----------------
// pd arithmetic bit-exact np (no FMA, sequential adds) — LOAD-BEARING, do not change.
__global__ __launch_bounds__(256) void knn_kernel(const float* __restrict__ ptsq, int* __restrict__ idx)
{
    int wid  = (blockIdx.x << 2) | (threadIdx.x >> 6);   // global wave id = b*N + i
    int lane = threadIdx.x & 63;
    int b = wid >> 12, i = wid & (N_ - 1);
    const float* pq = ptsq + (size_t)(b << 12) * 4;
    f32x4v qv = *reinterpret_cast<const f32x4v*>(pq + (size_t)i * 4);
    float xi = qv[0], yi = qv[1], zi = qv[2];
    float nxxi = -qv[3];

    float pd[64];                    // candidate j = c*64 + lane (statically indexed only)
    #pragma unroll
    for (int c = 0; c < 64; ++c) {
        f32x4v pv = *reinterpret_cast<const f32x4v*>(pq + (size_t)(c * 64 + lane) * 4);
        float px = __fmul_rn(xi, pv[0]);
        float py = __fmul_rn(yi, pv[1]);
        float pz = __fmul_rn(zi, pv[2]);
        float dot = __fadd_rn(__fadd_rn(px, py), pz);   // NO FMA — matches np
        float inner = __fmul_rn(-2.0f, dot);
        pd[c] = __fsub_rn(__fsub_rn(nxxi, inner), pv[3]);
    }

    // rank 0 = self: pd[i,i] = +0 exactly is the strict max; emit and retire
    {
        int slot = __builtin_amdgcn_readfirstlane(i >> 6);
        int ln   = __builtin_amdgcn_readfirstlane(i & 63);
        bool me = (lane == ln);
        #pragma unroll
        for (int c = 0; c < 64; ++c)
            if (c == slot) pd[c] = me ? -INFINITY : pd[c];
        if (lane == 0) idx[(size_t)b * NK_ + i] = i;
    }

    float gmax[8];
    #pragma unroll
    for (int g = 0; g < 8; ++g) {
        float m01 = fmaxf(pd[g * 8 + 0], pd[g * 8 + 1]);
        float m23 = fmaxf(pd[g * 8 + 2], pd[g * 8 + 3]);
        float m45 = fmaxf(pd[g * 8 + 4], pd[g * 8 + 5]);
        float m67 = fmaxf(pd[g * 8 + 6], pd[g * 8 + 7]);
        gmax[g] = fmaxf(fmaxf(m01, m23), fmaxf(m45, m67));
    }

    for (int it = 1; it < K_; ++it) {
        float a01 = fmaxf(gmax[0], gmax[1]);
        float a23 = fmaxf(gmax[2], gmax[3]);
        float a45 = fmaxf(gmax[4], gmax[5]);
        float a67 = fmaxf(gmax[6], gmax[7]);
        float vb = fmaxf(fmaxf(a01, a23), fmaxf(a45, a67));

        // wave max via DPP cascade (all VALU; lane 63 ends with global max)
        float r = vb;
        r = dppmax_step<0x111>(r);   // row_shr:1
        r = dppmax_step<0x112>(r);   // row_shr:2
        r = dppmax_step<0x114>(r);   // row_shr:4
        r = dppmax_step<0x118>(r);   // row_shr:8
        r = dppmax_step<0x142>(r);   // row_bcast15
        r = dppmax_step<0x143>(r);   // row_bcast31
        int wvi = __builtin_amdgcn_readlane(__float_as_int(r), 63);
        float wv = __int_as_float(wvi);                 // wave-uniform max value

        unsigned long long mk = __ballot(vb == wv);
        int wl = 63 - __builtin_clzll(mk);              // winner lane (uniform)

        int gsel = 0;
        #pragma unroll
        for (int g = 0; g < 8; ++g)
            if (gmax[g] == wv) gsel = g;
        int gw = __builtin_amdgcn_readlane(gsel, wl);

        int usel = 0;
        #pragma unroll
        for (int g = 0; g < 8; ++g)
            if (g == gw) {                               // gw uniform -> static branch
                #pragma unroll
                for (int u = 0; u < 8; ++u)
                    if (pd[g * 8 + u] == wv) usel = u;
            }
        int uw = __builtin_amdgcn_readlane(usel, wl);

        int bj = (gw * 8 + uw) * 64 + wl;
        if (lane == 0) idx[(size_t)b * NK_ + it * N_ + i] = bj;

        bool me = (lane == wl);
        #pragma unroll
        for (int g = 0; g < 8; ++g)
            if (g == gw) {
                #pragma unroll
                for (int u = 0; u < 8; ++u)
                    if (u == uw) pd[g * 8 + u] = me ? -INFINITY : pd[g * 8 + u];
                float m01 = fmaxf(pd[g * 8 + 0], pd[g * 8 + 1]);
                float m23 = fmaxf(pd[g * 8 + 2], pd[g * 8 + 3]);
                float m45 = fmaxf(pd[g * 8 + 4], pd[g * 8 + 5]);
                float m67 = fmaxf(pd[g * 8 + 6], pd[g * 8 + 7]);
                gmax[g] = fmaxf(fmaxf(m01, m23), fmaxf(m45, m67));
            }
    }
}

// ---------------- angle: "x<0" quadrant predicate — LOAD-BEARING (round 10) ----------------
__device__ inline float angle3(float ax, float ay, float az, float bx, float by, float bz)
{
    float cx = __fsub_rn(__fmul_rn(ay, bz), __fmul_rn(az, by));
    float cy = __fsub_rn(__fmul_rn(az, bx), __fmul_rn(ax, bz));
    float cz = __fsub_rn(__fmul_rn(ax, by), __fmul_rn(ay, bx));
    float cn = sqrtf(__fadd_rn(__fadd_rn(__fmul_rn(cx, cx), __fmul_rn(cy, cy)), __fmul_rn(cz, cz)));
    float d  = __fadd_rn(__fadd_rn(__fmul_rn(ax, bx), __fmul_rn(ay, by)), __fmul_rn(az, bz));
    if (cn == 0.0f)
        return (d < 0.0f) ? 3.14159274101257324e+00f : 0.0f;   // -0 -> 0
    return atan2f(cn, d);
}

__global__ __launch_bounds__(256) void feature_kernel(const float* __restrict__ pts,
                                                      const int* __restrict__ idx,
                                                      float* __restrict__ x0)
{
    int t = blockIdx.x * 256 + threadIdx.x;           // [0, B*NK)
    int col = t % NK_;
    int b = t / NK_;
    int n = col & (N_ - 1);
    int j = idx[t];
    const float* pb = pts + (size_t)b * 6 * N_;
    float cx = pb[n],            cy = pb[N_ + n],     cz = pb[2 * N_ + n];
    float gx = pb[j],            gy = pb[N_ + j],     gz = pb[2 * N_ + j];
    float rx = pb[3 * N_ + n],   ry = pb[4 * N_ + n], rz = pb[5 * N_ + n];
    float ix = pb[3 * N_ + j],   iy = pb[4 * N_ + j], iz = pb[5 * N_ + j];
    float lx = __fsub_rn(gx, cx), ly = __fsub_rn(gy, cy), lz = __fsub_rn(gz, cz);

    float f9  = angle3(rx, ry, rz, lx, ly, lz);
    float f10 = angle3(ix, iy, iz, lx, ly, lz);
    float f11 = angle3(rx, ry, rz, ix, iy, iz);
    float f12 = sqrtf(__fadd_rn(__fadd_rn(__fmul_rn(lx, lx), __fmul_rn(ly, ly)), __fmul_rn(lz, lz)));

    float* xp = x0 + (size_t)b * 13 * NK_ + col;
    xp[0  * (size_t)NK_] = gx;
    xp[1  * (size_t)NK_] = gy;
    xp[2  * (size_t)NK_] = gz;
    xp[3  * (size_t)NK_] = cx;
    xp[4  * (size_t)NK_] = cy;
    xp[5  * (size_t)NK_] = cz;
    xp[6  * (size_t)NK_] = lx;
    xp[7  * (size_t)NK_] = ly;
    xp[8  * (size_t)NK_] = lz;
    xp[9  * (size_t)NK_] = f9;
    xp[10 * (size_t)NK_] = f10;
    xp[11 * (size_t)NK_] = f11;
    xp[12 * (size_t)NK_] = f12;
}

// ---------------- deterministic block reduction: 16 sums + 16 sumsqs -> 32 partials ----------------
__device__ inline void block_reduce_write(const float gsum[16], const float gsq[16], float* __restrict__ dst)
{
    __shared__ float red[4][32];
    int t = threadIdx.x, lane = t & 63, w = t >> 6;
    #pragma unroll
    for (int r = 0; r < 16; ++r) {
        float v = gsum[r];
        #pragma unroll
        for (int off = 32; off > 0; off >>= 1) v += __shfl_down(v, off);
        if (lane == 0) red[w][r] = v;
        float q = gsq[r];
        #pragma unroll
        for (int off = 32; off > 0; off >>= 1) q += __shfl_down(q, off);
        if (lane == 0) red[w][16 + r] = q;
    }
    __syncthreads();
    if (t < 32) dst[t] = red[0][t] + red[1][t] + red[2][t] + red[3][t];
}

// ---------------- stage1: conv1 -> y1g raw bf16 [b][og=8][col][8] + GN1 partial stats ----------------
__global__ __launch_bounds__(256) void stage1_kernel(const float* __restrict__ x0,
    const float* __restrict__ W1, unsigned short* __restrict__ y1g, float* __restrict__ p1)
{
    int b = blockIdx.y;
    int col = blockIdx.x * 256 + threadIdx.x;
    const float* xb = x0 + (size_t)b * 13 * NK_ + col;
    float xr[13];
    #pragma unroll
    for (int c = 0; c < 13; ++c) xr[c] = xb[(size_t)c * NK_];
    float gsum[16], gsq[16];
    #pragma unroll
    for (int r = 0; r < 16; ++r) { gsum[r] = 0.f; gsq[r] = 0.f; }
    #pragma unroll
    for (int og = 0; og < 8; ++og) {
        u16x8v row;
        #pragma unroll
        for (int oi = 0; oi < 8; ++oi) {
            int o = og * 8 + oi;
            float acc = 0.f;
            #pragma unroll
            for (int c = 0; c < 13; ++c) acc = fmaf(W1[o * 13 + c], xr[c], acc);
            row[oi] = f2us(acc);
            gsum[og * 2 + (oi >> 2)] += acc;           // GN group o>>2, compile-time index
            gsq[og * 2 + (oi >> 2)] += acc * acc;      // stats on pre-rounding fp32
        }
        *reinterpret_cast<u16x8v*>(y1g + (((size_t)b * 8 + og) * NK_ + col) * 8) = row;
    }
    block_reduce_write(gsum, gsq, p1 + ((size_t)b * NBLK_ + blockIdx.x) * 32);
}

// ---------------- fold GN into per-(b,c) scale/shift from block partials: one WAVE per (b,c) ----------------
template<int COUT>
__global__ __launch_bounds__(256) void finalize_kernel(const float* __restrict__ part,
    const float* __restrict__ gamma, const float* __restrict__ beta,
    float* __restrict__ ga, float* __restrict__ sh)
{
    int wv = blockIdx.x * 4 + (threadIdx.x >> 6);   // wave id = b*COUT + c
    int lane = threadIdx.x & 63;
    int b = wv / COUT, c = wv % COUT;
    int g = c / (COUT / G_);
    float sum = 0.f, sq = 0.f;
    for (int blk = lane; blk < NBLK_; blk += 64) {
        const float* d = part + ((size_t)b * NBLK_ + blk) * 32;
        sum += d[g]; sq += d[16 + g];
    }
    #pragma unroll
    for (int off = 32; off > 0; off >>= 1) {
        sum += __shfl_down(sum, off);
        sq  += __shfl_down(sq, off);
    }
    if (lane == 0) {
        float cnt = (float)(COUT / G_) * (float)NK_;
        float mean = sum / cnt;
        float var = fmaxf(sq / cnt - mean * mean, 0.f);
        float sc = gamma[c] * rsqrtf(var + EPS_);
        ga[wv] = sc;
        sh[wv] = beta[c] - mean * sc;
    }
}

// ---------------- finalizeM: GN fold from MFMA partials [b][1024 sets][32] (e = 2g) ----------------
template<int COUT>
__global__ __launch_bounds__(256) void finalizeM_kernel(const float* __restrict__ pm,
    const float* __restrict__ gamma, const float* __restrict__ beta,
    float* __restrict__ ga, float* __restrict__ sh)
{
    int wv = blockIdx.x * 4 + (threadIdx.x >> 6);   // wave id = b*COUT + c
    int lane = threadIdx.x & 63;
    int b = wv / COUT, c = wv % COUT;
    int g = c / (COUT / G_);
    int e = g * 2;
    float sum = 0.f, sq = 0.f;
    for (int s = lane; s < 1024; s += 64) {
        const float* d = pm + ((size_t)(b * 1024 + s)) * 32;
        sum += d[e]; sq += d[e + 1];
    }
    #pragma unroll
    for (int off = 32; off > 0; off >>= 1) {
        sum += __shfl_down(sum, off);
        sq  += __shfl_down(sq, off);
    }
    if (lane == 0) {
        float cnt = (float)(COUT / G_) * (float)NK_;
        float mean = sum / cnt;
        float var = fmaxf(sq / cnt - mean * mean, 0.f);
        float sc = gamma[c] * rsqrtf(var + EPS_);
        ga[wv] = sc;
        sh[wv] = beta[c] - mean * sc;
    }
}

// ---------------- weight -> bf16 casts ----------------
__global__ __launch_bounds__(256) void wcast_kernel(const float* __restrict__ W, bf16* __restrict__ Wb, int n)
{
    int t = blockIdx.x * 256 + threadIdx.x;
    if (t < n) Wb[t] = f2b(W[t]);
}

// ---------------- prep64: in-place x = bf16(relu(a*y + s)) on 64-ch grouped [b][cg=8][col][8c] ----------------
__global__ __launch_bounds__(256) void prep64_kernel(unsigned short* __restrict__ yg,
    const float* __restrict__ a, const float* __restrict__ s)
{
    size_t t = (size_t)blockIdx.x * 256 + threadIdx.x;   // one (b,cg,col) 16B chunk
    int b  = (int)(t / ((size_t)8 * NK_));
    int cg = (int)((t / NK_) & 7);
    const float* ab = a + b * 64 + cg * 8;
    const float* sb = s + b * 64 + cg * 8;
    u16x8v v = *reinterpret_cast<const u16x8v*>(yg + t * 8);
    #pragma unroll
    for (int j = 0; j < 8; ++j)
        v[j] = f2us(fmaxf(fmaf(us2f(v[j]), ab[j], sb[j]), 0.f));
    *reinterpret_cast<u16x8v*>(yg + t * 8) = v;
}

// ---------------- stage2 via MFMA: y2 = W2(64x64) x x1 -> y2g grouped + GN2 partials ----------------
__global__ __launch_bounds__(256) void stage2_mfma_kernel(
    const short* __restrict__ x1g, const short* __restrict__ w2b,
    unsigned short* __restrict__ y2g, float* __restrict__ p2m)
{
    int ntile = blockIdx.x, b = blockIdx.z;
    int lane = threadIdx.x & 63, w = threadIdx.x >> 6;
    int colbase = ntile * 16 + (lane & 15);
    int cme = (lane >> 4) * 8;

    bf16x8v afr[4][2];
    #pragma unroll
    for (int ot = 0; ot < 4; ++ot)
        #pragma unroll
        for (int kb = 0; kb < 2; ++kb)
            afr[ot][kb] = *reinterpret_cast<const bf16x8v*>(
                w2b + (size_t)(ot * 16 + (lane & 15)) * 64 + kb * 32 + cme);

    float psum[4], psq[4];
    #pragma unroll
    for (int ot = 0; ot < 4; ++ot) { psum[ot] = 0.f; psq[ot] = 0.f; }

    for (int kk = 0; kk < 5; ++kk) {
        int k = kk * 4 + w;
        int colme = k * N_ + colbase;
        bf16x8v bfr[2];
        #pragma unroll
        for (int kb = 0; kb < 2; ++kb) {
            int cg = kb * 4 + (lane >> 4);
            bfr[kb] = *reinterpret_cast<const bf16x8v*>(
                x1g + (((size_t)b * 8 + cg) * NK_ + colme) * 8);
        }
        #pragma unroll
        for (int ot = 0; ot < 4; ++ot) {
            f32x4v acc = { 0.f, 0.f, 0.f, 0.f };
            acc = __builtin_amdgcn_mfma_f32_16x16x32_bf16(afr[ot][0], bfr[0], acc, 0, 0, 0);
            acc = __builtin_amdgcn_mfma_f32_16x16x32_bf16(afr[ot][1], bfr[1], acc, 0, 0, 0);
            u16x4v sv;
            #pragma unroll
            for (int j = 0; j < 4; ++j) {
                float v = acc[j];
                sv[j] = f2us(v);
                psum[ot] += v; psq[ot] += v * v;
            }
            int cgo = ot * 2 + (lane >> 5);           // output c-group (8ch)
            *reinterpret_cast<u16x4v*>(
                y2g + (((size_t)b * 8 + cgo) * NK_ + colme) * 8 + ((lane >> 4) & 1) * 4) = sv;
        }
    }
    float* dst = p2m + ((size_t)(b * 256 + ntile) * 4 + w) * 32;
    int qq = lane >> 4;
    #pragma unroll
    for (int ot = 0; ot < 4; ++ot) {
        float s = psum[ot], q = psq[ot];
        #pragma unroll
        for (int off = 8; off > 0; off >>= 1) {
            s += __shfl_down(s, off, 16);
            q += __shfl_down(q, off, 16);
        }
        if ((lane & 15) == 0) {
            dst[(ot * 4 + qq) * 2 + 0] = s;
            dst[(ot * 4 + qq) * 2 + 1] = q;
        }
    }
}

// ---------------- stage3 via MFMA: y3 = W3(128x64) x x2 -> y3g grouped + GN3 partials ----------------
__global__ __launch_bounds__(256) void stage3_mfma_kernel(
    const short* __restrict__ x2g, const short* __restrict__ w3b,
    unsigned short* __restrict__ y3g, float* __restrict__ p3m)
{
    int ntile = blockIdx.x, b = blockIdx.z;
    int lane = threadIdx.x & 63, w = threadIdx.x >> 6;
    int colbase = ntile * 16 + (lane & 15);
    int cme = (lane >> 4) * 8;

    bf16x8v afr[8][2];
    #pragma unroll
    for (int ot = 0; ot < 8; ++ot)
        #pragma unroll
        for (int kb = 0; kb < 2; ++kb)
            afr[ot][kb] = *reinterpret_cast<const bf16x8v*>(
                w3b + (size_t)(ot * 16 + (lane & 15)) * 64 + kb * 32 + cme);

    float psum[8], psq[8];
    #pragma unroll
    for (int ot = 0; ot < 8; ++ot) { psum[ot] = 0.f; psq[ot] = 0.f; }

    for (int kk = 0; kk < 5; ++kk) {
        int k = kk * 4 + w;
        int colme = k * N_ + colbase;
        bf16x8v bfr[2];
        #pragma unroll
        for (int kb = 0; kb < 2; ++kb) {
            int cg = kb * 4 + (lane >> 4);
            bfr[kb] = *reinterpret_cast<const bf16x8v*>(
                x2g + (((size_t)b * 8 + cg) * NK_ + colme) * 8);
        }
        #pragma unroll
        for (int ot = 0; ot < 8; ++ot) {
            f32x4v acc = { 0.f, 0.f, 0.f, 0.f };
            acc = __builtin_amdgcn_mfma_f32_16x16x32_bf16(afr[ot][0], bfr[0], acc, 0, 0, 0);
            acc = __builtin_amdgcn_mfma_f32_16x16x32_bf16(afr[ot][1], bfr[1], acc, 0, 0, 0);
            u16x4v sv;
            #pragma unroll
            for (int j = 0; j < 4; ++j) {
                float v = acc[j];
                sv[j] = f2us(v);
                psum[ot] += v; psq[ot] += v * v;
            }
            int g = ot * 2 + (lane >> 5);
            *reinterpret_cast<u16x4v*>(
                y3g + (((size_t)b * 16 + g) * NK_ + colme) * 8 + ((lane >> 4) & 1) * 4) = sv;
        }
    }
    float* dst = p3m + ((size_t)(b * 256 + ntile) * 4 + w) * 32;
    #pragma unroll
    for (int ot = 0; ot < 8; ++ot) {
        float s = psum[ot], q = psq[ot];
        #pragma unroll
        for (int off = 16; off > 0; off >>= 1) {
            s += __shfl_down(s, off, 32);
            q += __shfl_down(q, off, 32);
        }
        if ((lane & 31) == 0) {
            int half = lane >> 5;
            dst[ot * 4 + half * 2 + 0] = s;
            dst[ot * 4 + half * 2 + 1] = q;
        }
    }
}

// ---------------- prep4: in-place x3 = bf16(relu(a3*y3 + s3)) on y3g [b][cg=16][col][8c] ----------------
__global__ __launch_bounds__(256) void prep4_kernel(unsigned short* __restrict__ y3g,
    const float* __restrict__ a3, const float* __restrict__ s3)
{
    size_t t = (size_t)blockIdx.x * 256 + threadIdx.x;   // one (b,cg,col) 16B chunk
    int b  = (int)(t / ((size_t)16 * NK_));
    int cg = (int)((t / NK_) & 15);
    const float* ab = a3 + b * 128 + cg * 8;
    const float* sb = s3 + b * 128 + cg * 8;
    u16x8v v = *reinterpret_cast<const u16x8v*>(y3g + t * 8);
    #pragma unroll
    for (int j = 0; j < 8; ++j)
        v[j] = f2us(fmaxf(fmaf(us2f(v[j]), ab[j], sb[j]), 0.f));
    *reinterpret_cast<u16x8v*>(y3g + t * 8) = v;
}

// ---------------- conv4 via MFMA: block = 16n tile, 4 waves x 4 o-passes = all 256 o ----------------
__global__ __launch_bounds__(256) void conv4_mfma_kernel(
    const short* __restrict__ x3g, const short* __restrict__ w4b,
    float* __restrict__ m4, float* __restrict__ part)
{
    int ntile = blockIdx.x, b = blockIdx.z;
    int lane = threadIdx.x & 63, w = threadIdx.x >> 6;
    int colme = ntile * 16 + (lane & 15);
    int cme = (lane >> 4) * 8;

    bf16x8v afr[4][4];
    #pragma unroll
    for (int p = 0; p < 4; ++p) {
        #pragma unroll
        for (int cb = 0; cb < 4; ++cb) {
            size_t aoff = (size_t)(p * 64 + w * 16 + (lane & 15)) * 128 + cb * 32 + cme;
            afr[p][cb] = *reinterpret_cast<const bf16x8v*>(w4b + aoff);
        }
    }

    float am[4][4];
    #pragma unroll
    for (int p = 0; p < 4; ++p)
        #pragma unroll
        for (int j = 0; j < 4; ++j) am[p][j] = -INFINITY;
    float ps[4] = {0.f, 0.f, 0.f, 0.f}, pq[4] = {0.f, 0.f, 0.f, 0.f};

    for (int k = 0; k < K_; ++k) {
        bf16x8v bfr[4];
        #pragma unroll
        for (int cb = 0; cb < 4; ++cb) {
            int cg = cb * 4 + (lane >> 4);
            bfr[cb] = *reinterpret_cast<const bf16x8v*>(
                x3g + (((size_t)b * 16 + cg) * NK_ + (size_t)k * N_ + colme) * 8);
        }
        #pragma unroll
        for (int p = 0; p < 4; ++p) {
            f32x4v acc = { 0.f, 0.f, 0.f, 0.f };
            #pragma unroll
            for (int cb = 0; cb < 4; ++cb)
                acc = __builtin_amdgcn_mfma_f32_16x16x32_bf16(afr[p][cb], bfr[cb], acc, 0, 0, 0);
            #pragma unroll
            for (int j = 0; j < 4; ++j) {
                float v = acc[j];
                am[p][j] = fmaxf(am[p][j], v);
                ps[p] += v; pq[p] += v * v;
            }
        }
    }
    #pragma unroll
    for (int p = 0; p < 4; ++p) {
        #pragma unroll
        for (int j = 0; j < 4; ++j) {
            int o = p * 64 + w * 16 + (lane >> 4) * 4 + j;
            m4[((size_t)b * 256 + o) * N_ + colme] = am[p][j];
        }
        float s = ps[p], q = pq[p];
        #pragma unroll
        for (int off = 32; off > 0; off >>= 1) {
            s += __shfl_down(s, off);
            q += __shfl_down(q, off);
        }
        if (lane == 0) {
            int g = p * 4 + w;
            part[((b * 16 + g) * 2 + 0) * 256 + ntile] = s;
            part[((b * 16 + g) * 2 + 1) * 256 + ntile] = q;
        }
    }
}

// ---------------- GN4 finalize: one WAVE per (b,c), coalesced 256-entry rows ----------------
__global__ __launch_bounds__(256) void finalize4_kernel(const float* __restrict__ part,
    const float* __restrict__ gamma, const float* __restrict__ beta,
    float* __restrict__ ga, float* __restrict__ sh)
{
    int wv = blockIdx.x * 4 + (threadIdx.x >> 6);   // 0..1023 = b*256 + c
    int lane = threadIdx.x & 63;
    int b = wv >> 8, c = wv & 255;
    int g = c >> 4;
    float sum = 0.f, sq = 0.f;
    for (int nt = lane; nt < 256; nt += 64) {
        sum += part[((b * 16 + g) * 2 + 0) * 256 + nt];
        sq  += part[((b * 16 + g) * 2 + 1) * 256 + nt];
    }
    #pragma unroll
    for (int off = 32; off > 0; off >>= 1) {
        sum += __shfl_down(sum, off);
        sq  += __shfl_down(sq, off);
    }
    if (lane == 0) {
        float cnt = 16.f * (float)NK_;
        float mean = sum / cnt;
        float var = fmaxf(sq / cnt - mean * mean, 0.f);
        float sc = gamma[c] * rsqrtf(var + EPS_);
        ga[wv] = sc;
        sh[wv] = beta[c] - mean * sc;
    }
}

// ---------------- final: out = relu(a*max_k + s)  (valid since a>0) ----------------
__global__ __launch_bounds__(256) void apply_kernel(const float* __restrict__ m4,
    const float* __restrict__ ga, const float* __restrict__ sh, float* __restrict__ out)
{
    int t = blockIdx.x * 256 + threadIdx.x;   // b*256*N + c*N + n
    int bc = t >> 12;
    out[t] = fmaxf(fmaf(m4[t], ga[bc], sh[bc]), 0.f);
}

extern "C" void kernel_launch(void* const* d_in, const int* in_sizes, int n_in,
                              void* d_out, int out_size, void* d_ws, size_t ws_size,
                              hipStream_t stream)
{
    const float* pts = (const float*)d_in[0];
    const float* W1 = (const float*)d_in[1];
    const float* g1 = (const float*)d_in[2];
    const float* bt1 = (const float*)d_in[3];
    const float* W2 = (const float*)d_in[4];
    const float* g2 = (const float*)d_in[5];
    const float* bt2 = (const float*)d_in[6];
    const float* W3 = (const float*)d_in[7];
    const float* g3 = (const float*)d_in[8];
    const float* bt3 = (const float*)d_in[9];
    const float* W4 = (const float*)d_in[10];
    const float* g4 = (const float*)d_in[11];
    const float* bt4 = (const float*)d_in[12];
    float* out = (float*)d_out;

    char* ws = (char*)d_ws;
    size_t off = 0;
    auto alloc = [&](size_t bytes) -> void* {
        void* p = ws + off;
        off = (off + bytes + 255) & ~(size_t)255;
        return p;
    };
    int*   idx  = (int*)  alloc((size_t)B_ * NK_ * 4);           // 1.3 MB
    float* ptsq = (float*)alloc((size_t)B_ * N_ * 4 * 4);        // 256 KB
    float* x0   = (float*)alloc((size_t)B_ * 13 * NK_ * 4);      // 17 MB
    unsigned short* y2g = (unsigned short*)alloc((size_t)B_ * 8 * NK_ * 8 * 2);   // 42 MB
    unsigned short* y3g = (unsigned short*)alloc((size_t)B_ * 16 * NK_ * 8 * 2);  // 84 MB
    unsigned short* y1g = y3g;   // ALIAS: y1g (42 MB) lives in y3g's buffer; dead before stage3 writes
    float* m4   = (float*)alloc((size_t)B_ * 256 * N_ * 4);      // 16.8 MB
    bf16*  w2b  = (bf16*) alloc(64 * 64 * 2);                    // 8 KB
    bf16*  w3b  = (bf16*) alloc(128 * 64 * 2);                   // 16 KB
    bf16*  w4b  = (bf16*) alloc(256 * 128 * 2);                  // 64 KB
    float* p1   = (float*)alloc((size_t)B_ * NBLK_ * 32 * 4);    // 164 KB
    float* p2m  = (float*)alloc((size_t)B_ * 1024 * 32 * 4);     // 0.5 MB
    float* p3m  = (float*)alloc((size_t)B_ * 1024 * 32 * 4);     // 0.5 MB
    float* part4= (float*)alloc(4 * 16 * 2 * 256 * 4);           // 128 KB
    float* a1 = (float*)alloc(B_ * 64 * 4);
    float* s1 = (float*)alloc(B_ * 64 * 4);
    float* a2 = (float*)alloc(B_ * 64 * 4);
    float* s2 = (float*)alloc(B_ * 64 * 4);
    float* a3 = (float*)alloc(B_ * 128 * 4);
    float* s3 = (float*)alloc(B_ * 128 * 4);
    float* a4 = (float*)alloc(B_ * 256 * 4);
    float* s4 = (float*)alloc(B_ * 256 * 4);
    (void)ws_size; (void)in_sizes; (void)n_in; (void)out_size;

    ptsq_kernel<<<(B_ * N_) / 256, 256, 0, stream>>>(pts, ptsq);
    knn_kernel<<<(B_ * N_) / 4, 256, 0, stream>>>(ptsq, idx);
    wcast_kernel<<<16, 256, 0, stream>>>(W2, w2b, 64 * 64);
    wcast_kernel<<<32, 256, 0, stream>>>(W3, w3b, 128 * 64);
    wcast_kernel<<<128, 256, 0, stream>>>(W4, w4b, 256 * 128);
    feature_kernel<<<(B_ * NK_) / 256, 256, 0, stream>>>(pts, idx, x0);

    stage1_kernel<<<dim3(NBLK_, B_), 256, 0, stream>>>(x0, W1, y1g, p1);
    finalize_kernel<64><<<64, 256, 0, stream>>>(p1, g1, bt1, a1, s1);

    prep64_kernel<<<(int)(((size_t)B_ * 8 * NK_) / 256), 256, 0, stream>>>(y1g, a1, s1);
    stage2_mfma_kernel<<<dim3(N_ / 16, 1, B_), 256, 0, stream>>>((const short*)y1g, (const short*)w2b, y2g, p2m);
    finalizeM_kernel<64><<<64, 256, 0, stream>>>(p2m, g2, bt2, a2, s2);

    prep64_kernel<<<(int)(((size_t)B_ * 8 * NK_) / 256), 256, 0, stream>>>(y2g, a2, s2);
    stage3_mfma_kernel<<<dim3(N_ / 16, 1, B_), 256, 0, stream>>>((const short*)y2g, (const short*)w3b, y3g, p3m);
    finalizeM_kernel<128><<<128, 256, 0, stream>>>(p3m, g3, bt3, a3, s3);

    prep4_kernel<<<(int)(((size_t)B_ * 16 * NK_) / 256), 256, 0, stream>>>(y3g, a3, s3);
    conv4_mfma_kernel<<<dim3(N_ / 16, 1, B_), 256, 0, stream>>>((const short*)y3g, (const short*)w4b, m4, part4);
    finalize4_kernel<<<256, 256, 0, stream>>>(part4, g4, bt4, a4, s4);

    apply_kernel<<<(B_ * 256 * N_) / 256, 256, 0, stream>>>(m4, a4, s4, out);
}

// Round 23
// 450.056 us; speedup vs baseline: 1.0265x; 1.0265x over previous
//
#include <hip/hip_runtime.h>
#include <hip/hip_bf16.h>
#include <math.h>

#define B_ 4
#define N_ 4096
#define K_ 20
#define NK_ (N_*K_)   // 81920
#define G_ 16
#define EPS_ 1e-5f
#define NBLK_ (NK_/256)   // 320 column-blocks per batch

typedef __hip_bfloat16 bf16;
typedef short bf16x8v __attribute__((ext_vector_type(8)));
typedef unsigned short u16x8v __attribute__((ext_vector_type(8)));
typedef unsigned short u16x4v __attribute__((ext_vector_type(4)));
typedef float f32x4v __attribute__((ext_vector_type(4)));

__device__ inline float b2f(bf16 v) { return __bfloat162float(v); }
__device__ inline bf16  f2b(float v){ return __float2bfloat16(v); }
__device__ inline float us2f(unsigned short u){ unsigned int i = ((unsigned)u) << 16; float f; __builtin_memcpy(&f, &i, 4); return f; }
__device__ inline unsigned short f2us(float f){ bf16 h = __float2bfloat16(f); unsigned short u; __builtin_memcpy(&u, &h, 2); return u; }

template<int CTRL>
__device__ inline float dppmax_step(float v)
{
    int i; __builtin_memcpy(&i, &v, 4);
    int m = __builtin_amdgcn_update_dpp((int)0xFF800000, i, CTRL, 0xF, 0xF, false);
    float f; __builtin_memcpy(&f, &m, 4);
    return fmaxf(v, f);
}

// ---------------- kNN: one WAVE per (b,i); two-level cache + DPP (r21 WIN, reverted) ----------------
// pd arithmetic bit-exact np (no FMA, sequential adds) — LOAD-BEARING, do not change.
// r22 lesson: VGPR>104 halves occupancy and regresses; scalar loads are already coalesced.
__global__ __launch_bounds__(256) __attribute__((amdgpu_waves_per_eu(5)))
void knn_kernel(const float* __restrict__ pts, int* __restrict__ idx)
{
    int wid  = (blockIdx.x << 2) | (threadIdx.x >> 6);   // global wave id = b*N + i
    int lane = threadIdx.x & 63;
    int b = wid >> 12, i = wid & (N_ - 1);
    const float* pb = pts + (size_t)b * 6 * N_;
    float xi = pb[i], yi = pb[N_ + i], zi = pb[2 * N_ + i];
    float xxi = __fadd_rn(__fadd_rn(__fmul_rn(xi, xi), __fmul_rn(yi, yi)), __fmul_rn(zi, zi));
    float nxxi = -xxi;

    float pd[64];                    // candidate j = c*64 + lane (statically indexed only)
    #pragma unroll
    for (int c = 0; c < 64; ++c) {
        int j = c * 64 + lane;
        float xj = pb[j], yj = pb[N_ + j], zj = pb[2 * N_ + j];
        float xxj = __fadd_rn(__fadd_rn(__fmul_rn(xj, xj), __fmul_rn(yj, yj)), __fmul_rn(zj, zj));
        float px = __fmul_rn(xi, xj);
        float py = __fmul_rn(yi, yj);
        float pz = __fmul_rn(zi, zj);
        float dot = __fadd_rn(__fadd_rn(px, py), pz);   // NO FMA — matches np
        float inner = __fmul_rn(-2.0f, dot);
        pd[c] = __fsub_rn(__fsub_rn(nxxi, inner), xxj);
    }

    // rank 0 = self: pd[i,i] = +0 exactly is the strict max; emit and retire
    {
        int slot = __builtin_amdgcn_readfirstlane(i >> 6);
        int ln   = __builtin_amdgcn_readfirstlane(i & 63);
        bool me = (lane == ln);
        #pragma unroll
        for (int c = 0; c < 64; ++c)
            if (c == slot) pd[c] = me ? -INFINITY : pd[c];
        if (lane == 0) idx[(size_t)b * NK_ + i] = i;
    }

    float gmax[8];
    #pragma unroll
    for (int g = 0; g < 8; ++g) {
        float m01 = fmaxf(pd[g * 8 + 0], pd[g * 8 + 1]);
        float m23 = fmaxf(pd[g * 8 + 2], pd[g * 8 + 3]);
        float m45 = fmaxf(pd[g * 8 + 4], pd[g * 8 + 5]);
        float m67 = fmaxf(pd[g * 8 + 6], pd[g * 8 + 7]);
        gmax[g] = fmaxf(fmaxf(m01, m23), fmaxf(m45, m67));
    }

    for (int it = 1; it < K_; ++it) {
        float a01 = fmaxf(gmax[0], gmax[1]);
        float a23 = fmaxf(gmax[2], gmax[3]);
        float a45 = fmaxf(gmax[4], gmax[5]);
        float a67 = fmaxf(gmax[6], gmax[7]);
        float vb = fmaxf(fmaxf(a01, a23), fmaxf(a45, a67));

        // wave max via DPP cascade (all VALU; lane 63 ends with global max)
        float r = vb;
        r = dppmax_step<0x111>(r);   // row_shr:1
        r = dppmax_step<0x112>(r);   // row_shr:2
        r = dppmax_step<0x114>(r);   // row_shr:4
        r = dppmax_step<0x118>(r);   // row_shr:8
        r = dppmax_step<0x142>(r);   // row_bcast15
        r = dppmax_step<0x143>(r);   // row_bcast31
        int wvi = __builtin_amdgcn_readlane(__float_as_int(r), 63);
        float wv = __int_as_float(wvi);                 // wave-uniform max value

        unsigned long long mk = __ballot(vb == wv);
        int wl = 63 - __builtin_clzll(mk);              // winner lane (uniform)

        int gsel = 0;
        #pragma unroll
        for (int g = 0; g < 8; ++g)
            if (gmax[g] == wv) gsel = g;
        int gw = __builtin_amdgcn_readlane(gsel, wl);

        int usel = 0;
        #pragma unroll
        for (int g = 0; g < 8; ++g)
            if (g == gw) {                               // gw uniform -> static branch
                #pragma unroll
                for (int u = 0; u < 8; ++u)
                    if (pd[g * 8 + u] == wv) usel = u;
            }
        int uw = __builtin_amdgcn_readlane(usel, wl);

        int bj = (gw * 8 + uw) * 64 + wl;
        if (lane == 0) idx[(size_t)b * NK_ + it * N_ + i] = bj;

        bool me = (lane == wl);
        #pragma unroll
        for (int g = 0; g < 8; ++g)
            if (g == gw) {
                #pragma unroll
                for (int u = 0; u < 8; ++u)
                    if (u == uw) pd[g * 8 + u] = me ? -INFINITY : pd[g * 8 + u];
                float m01 = fmaxf(pd[g * 8 + 0], pd[g * 8 + 1]);
                float m23 = fmaxf(pd[g * 8 + 2], pd[g * 8 + 3]);
                float m45 = fmaxf(pd[g * 8 + 4], pd[g * 8 + 5]);
                float m67 = fmaxf(pd[g * 8 + 6], pd[g * 8 + 7]);
                gmax[g] = fmaxf(fmaxf(m01, m23), fmaxf(m45, m67));
            }
    }
}

// ---------------- angle: "x<0" quadrant predicate — LOAD-BEARING (round 10) ----------------
__device__ inline float angle3(float ax, float ay, float az, float bx, float by, float bz)
{
    float cx = __fsub_rn(__fmul_rn(ay, bz), __fmul_rn(az, by));
    float cy = __fsub_rn(__fmul_rn(az, bx), __fmul_rn(ax, bz));
    float cz = __fsub_rn(__fmul_rn(ax, by), __fmul_rn(ay, bx));
    float cn = sqrtf(__fadd_rn(__fadd_rn(__fmul_rn(cx, cx), __fmul_rn(cy, cy)), __fmul_rn(cz, cz)));
    float d  = __fadd_rn(__fadd_rn(__fmul_rn(ax, bx), __fmul_rn(ay, by)), __fmul_rn(az, bz));
    if (cn == 0.0f)
        return (d < 0.0f) ? 3.14159274101257324e+00f : 0.0f;   // -0 -> 0
    return atan2f(cn, d);
}

__global__ __launch_bounds__(256) void feature_kernel(const float* __restrict__ pts,
                                                      const int* __restrict__ idx,
                                                      float* __restrict__ x0)
{
    int t = blockIdx.x * 256 + threadIdx.x;           // [0, B*NK)
    int col = t % NK_;
    int b = t / NK_;
    int n = col & (N_ - 1);
    int j = idx[t];
    const float* pb = pts + (size_t)b * 6 * N_;
    float cx = pb[n],            cy = pb[N_ + n],     cz = pb[2 * N_ + n];
    float gx = pb[j],            gy = pb[N_ + j],     gz = pb[2 * N_ + j];
    float rx = pb[3 * N_ + n],   ry = pb[4 * N_ + n], rz = pb[5 * N_ + n];
    float ix = pb[3 * N_ + j],   iy = pb[4 * N_ + j], iz = pb[5 * N_ + j];
    float lx = __fsub_rn(gx, cx), ly = __fsub_rn(gy, cy), lz = __fsub_rn(gz, cz);

    float f9  = angle3(rx, ry, rz, lx, ly, lz);
    float f10 = angle3(ix, iy, iz, lx, ly, lz);
    float f11 = angle3(rx, ry, rz, ix, iy, iz);
    float f12 = sqrtf(__fadd_rn(__fadd_rn(__fmul_rn(lx, lx), __fmul_rn(ly, ly)), __fmul_rn(lz, lz)));

    float* xp = x0 + (size_t)b * 13 * NK_ + col;
    xp[0  * (size_t)NK_] = gx;
    xp[1  * (size_t)NK_] = gy;
    xp[2  * (size_t)NK_] = gz;
    xp[3  * (size_t)NK_] = cx;
    xp[4  * (size_t)NK_] = cy;
    xp[5  * (size_t)NK_] = cz;
    xp[6  * (size_t)NK_] = lx;
    xp[7  * (size_t)NK_] = ly;
    xp[8  * (size_t)NK_] = lz;
    xp[9  * (size_t)NK_] = f9;
    xp[10 * (size_t)NK_] = f10;
    xp[11 * (size_t)NK_] = f11;
    xp[12 * (size_t)NK_] = f12;
}

// ---------------- deterministic block reduction: 16 sums + 16 sumsqs -> 32 partials ----------------
__device__ inline void block_reduce_write(const float gsum[16], const float gsq[16], float* __restrict__ dst)
{
    __shared__ float red[4][32];
    int t = threadIdx.x, lane = t & 63, w = t >> 6;
    #pragma unroll
    for (int r = 0; r < 16; ++r) {
        float v = gsum[r];
        #pragma unroll
        for (int off = 32; off > 0; off >>= 1) v += __shfl_down(v, off);
        if (lane == 0) red[w][r] = v;
        float q = gsq[r];
        #pragma unroll
        for (int off = 32; off > 0; off >>= 1) q += __shfl_down(q, off);
        if (lane == 0) red[w][16 + r] = q;
    }
    __syncthreads();
    if (t < 32) dst[t] = red[0][t] + red[1][t] + red[2][t] + red[3][t];
}

// ---------------- stage1: conv1 -> y1g raw bf16 [b][og=8][col][8] + GN1 partial stats ----------------
__global__ __launch_bounds__(256) void stage1_kernel(const float* __restrict__ x0,
    const float* __restrict__ W1, unsigned short* __restrict__ y1g, float* __restrict__ p1)
{
    int b = blockIdx.y;
    int col = blockIdx.x * 256 + threadIdx.x;
    const float* xb = x0 + (size_t)b * 13 * NK_ + col;
    float xr[13];
    #pragma unroll
    for (int c = 0; c < 13; ++c) xr[c] = xb[(size_t)c * NK_];
    float gsum[16], gsq[16];
    #pragma unroll
    for (int r = 0; r < 16; ++r) { gsum[r] = 0.f; gsq[r] = 0.f; }
    #pragma unroll
    for (int og = 0; og < 8; ++og) {
        u16x8v row;
        #pragma unroll
        for (int oi = 0; oi < 8; ++oi) {
            int o = og * 8 + oi;
            float acc = 0.f;
            #pragma unroll
            for (int c = 0; c < 13; ++c) acc = fmaf(W1[o * 13 + c], xr[c], acc);
            row[oi] = f2us(acc);
            gsum[og * 2 + (oi >> 2)] += acc;           // GN group o>>2, compile-time index
            gsq[og * 2 + (oi >> 2)] += acc * acc;      // stats on pre-rounding fp32
        }
        *reinterpret_cast<u16x8v*>(y1g + (((size_t)b * 8 + og) * NK_ + col) * 8) = row;
    }
    block_reduce_write(gsum, gsq, p1 + ((size_t)b * NBLK_ + blockIdx.x) * 32);
}

// ---------------- fold GN into per-(b,c) scale/shift from block partials: one WAVE per (b,c) ----------------
template<int COUT>
__global__ __launch_bounds__(256) void finalize_kernel(const float* __restrict__ part,
    const float* __restrict__ gamma, const float* __restrict__ beta,
    float* __restrict__ ga, float* __restrict__ sh)
{
    int wv = blockIdx.x * 4 + (threadIdx.x >> 6);   // wave id = b*COUT + c
    int lane = threadIdx.x & 63;
    int b = wv / COUT, c = wv % COUT;
    int g = c / (COUT / G_);
    float sum = 0.f, sq = 0.f;
    for (int blk = lane; blk < NBLK_; blk += 64) {
        const float* d = part + ((size_t)b * NBLK_ + blk) * 32;
        sum += d[g]; sq += d[16 + g];
    }
    #pragma unroll
    for (int off = 32; off > 0; off >>= 1) {
        sum += __shfl_down(sum, off);
        sq  += __shfl_down(sq, off);
    }
    if (lane == 0) {
        float cnt = (float)(COUT / G_) * (float)NK_;
        float mean = sum / cnt;
        float var = fmaxf(sq / cnt - mean * mean, 0.f);
        float sc = gamma[c] * rsqrtf(var + EPS_);
        ga[wv] = sc;
        sh[wv] = beta[c] - mean * sc;
    }
}

// ---------------- finalizeM: GN fold from MFMA partials [b][1024 sets][32] (e = 2g) ----------------
template<int COUT>
__global__ __launch_bounds__(256) void finalizeM_kernel(const float* __restrict__ pm,
    const float* __restrict__ gamma, const float* __restrict__ beta,
    float* __restrict__ ga, float* __restrict__ sh)
{
    int wv = blockIdx.x * 4 + (threadIdx.x >> 6);   // wave id = b*COUT + c
    int lane = threadIdx.x & 63;
    int b = wv / COUT, c = wv % COUT;
    int g = c / (COUT / G_);
    int e = g * 2;
    float sum = 0.f, sq = 0.f;
    for (int s = lane; s < 1024; s += 64) {
        const float* d = pm + ((size_t)(b * 1024 + s)) * 32;
        sum += d[e]; sq += d[e + 1];
    }
    #pragma unroll
    for (int off = 32; off > 0; off >>= 1) {
        sum += __shfl_down(sum, off);
        sq  += __shfl_down(sq, off);
    }
    if (lane == 0) {
        float cnt = (float)(COUT / G_) * (float)NK_;
        float mean = sum / cnt;
        float var = fmaxf(sq / cnt - mean * mean, 0.f);
        float sc = gamma[c] * rsqrtf(var + EPS_);
        ga[wv] = sc;
        sh[wv] = beta[c] - mean * sc;
    }
}

// ---------------- weight -> bf16 casts ----------------
__global__ __launch_bounds__(256) void wcast_kernel(const float* __restrict__ W, bf16* __restrict__ Wb, int n)
{
    int t = blockIdx.x * 256 + threadIdx.x;
    if (t < n) Wb[t] = f2b(W[t]);
}

// ---------------- prep64: in-place x = bf16(relu(a*y + s)) on 64-ch grouped [b][cg=8][col][8c] ----------------
__global__ __launch_bounds__(256) void prep64_kernel(unsigned short* __restrict__ yg,
    const float* __restrict__ a, const float* __restrict__ s)
{
    size_t t = (size_t)blockIdx.x * 256 + threadIdx.x;   // one (b,cg,col) 16B chunk
    int b  = (int)(t / ((size_t)8 * NK_));
    int cg = (int)((t / NK_) & 7);
    const float* ab = a + b * 64 + cg * 8;
    const float* sb = s + b * 64 + cg * 8;
    u16x8v v = *reinterpret_cast<const u16x8v*>(yg + t * 8);
    #pragma unroll
    for (int j = 0; j < 8; ++j)
        v[j] = f2us(fmaxf(fmaf(us2f(v[j]), ab[j], sb[j]), 0.f));
    *reinterpret_cast<u16x8v*>(yg + t * 8) = v;
}

// ---------------- stage2 via MFMA: y2 = W2(64x64) x x1 -> y2g grouped + GN2 partials ----------------
__global__ __launch_bounds__(256) void stage2_mfma_kernel(
    const short* __restrict__ x1g, const short* __restrict__ w2b,
    unsigned short* __restrict__ y2g, float* __restrict__ p2m)
{
    int ntile = blockIdx.x, b = blockIdx.z;
    int lane = threadIdx.x & 63, w = threadIdx.x >> 6;
    int colbase = ntile * 16 + (lane & 15);
    int cme = (lane >> 4) * 8;

    bf16x8v afr[4][2];
    #pragma unroll
    for (int ot = 0; ot < 4; ++ot)
        #pragma unroll
        for (int kb = 0; kb < 2; ++kb)
            afr[ot][kb] = *reinterpret_cast<const bf16x8v*>(
                w2b + (size_t)(ot * 16 + (lane & 15)) * 64 + kb * 32 + cme);

    float psum[4], psq[4];
    #pragma unroll
    for (int ot = 0; ot < 4; ++ot) { psum[ot] = 0.f; psq[ot] = 0.f; }

    for (int kk = 0; kk < 5; ++kk) {
        int k = kk * 4 + w;
        int colme = k * N_ + colbase;
        bf16x8v bfr[2];
        #pragma unroll
        for (int kb = 0; kb < 2; ++kb) {
            int cg = kb * 4 + (lane >> 4);
            bfr[kb] = *reinterpret_cast<const bf16x8v*>(
                x1g + (((size_t)b * 8 + cg) * NK_ + colme) * 8);
        }
        #pragma unroll
        for (int ot = 0; ot < 4; ++ot) {
            f32x4v acc = { 0.f, 0.f, 0.f, 0.f };
            acc = __builtin_amdgcn_mfma_f32_16x16x32_bf16(afr[ot][0], bfr[0], acc, 0, 0, 0);
            acc = __builtin_amdgcn_mfma_f32_16x16x32_bf16(afr[ot][1], bfr[1], acc, 0, 0, 0);
            u16x4v sv;
            #pragma unroll
            for (int j = 0; j < 4; ++j) {
                float v = acc[j];
                sv[j] = f2us(v);
                psum[ot] += v; psq[ot] += v * v;
            }
            int cgo = ot * 2 + (lane >> 5);           // output c-group (8ch)
            *reinterpret_cast<u16x4v*>(
                y2g + (((size_t)b * 8 + cgo) * NK_ + colme) * 8 + ((lane >> 4) & 1) * 4) = sv;
        }
    }
    float* dst = p2m + ((size_t)(b * 256 + ntile) * 4 + w) * 32;
    int qq = lane >> 4;
    #pragma unroll
    for (int ot = 0; ot < 4; ++ot) {
        float s = psum[ot], q = psq[ot];
        #pragma unroll
        for (int off = 8; off > 0; off >>= 1) {
            s += __shfl_down(s, off, 16);
            q += __shfl_down(q, off, 16);
        }
        if ((lane & 15) == 0) {
            dst[(ot * 4 + qq) * 2 + 0] = s;
            dst[(ot * 4 + qq) * 2 + 1] = q;
        }
    }
}

// ---------------- stage3 via MFMA: y3 = W3(128x64) x x2 -> y3g grouped + GN3 partials ----------------
__global__ __launch_bounds__(256) void stage3_mfma_kernel(
    const short* __restrict__ x2g, const short* __restrict__ w3b,
    unsigned short* __restrict__ y3g, float* __restrict__ p3m)
{
    int ntile = blockIdx.x, b = blockIdx.z;
    int lane = threadIdx.x & 63, w = threadIdx.x >> 6;
    int colbase = ntile * 16 + (lane & 15);
    int cme = (lane >> 4) * 8;

    bf16x8v afr[8][2];
    #pragma unroll
    for (int ot = 0; ot < 8; ++ot)
        #pragma unroll
        for (int kb = 0; kb < 2; ++kb)
            afr[ot][kb] = *reinterpret_cast<const bf16x8v*>(
                w3b + (size_t)(ot * 16 + (lane & 15)) * 64 + kb * 32 + cme);

    float psum[8], psq[8];
    #pragma unroll
    for (int ot = 0; ot < 8; ++ot) { psum[ot] = 0.f; psq[ot] = 0.f; }

    for (int kk = 0; kk < 5; ++kk) {
        int k = kk * 4 + w;
        int colme = k * N_ + colbase;
        bf16x8v bfr[2];
        #pragma unroll
        for (int kb = 0; kb < 2; ++kb) {
            int cg = kb * 4 + (lane >> 4);
            bfr[kb] = *reinterpret_cast<const bf16x8v*>(
                x2g + (((size_t)b * 8 + cg) * NK_ + colme) * 8);
        }
        #pragma unroll
        for (int ot = 0; ot < 8; ++ot) {
            f32x4v acc = { 0.f, 0.f, 0.f, 0.f };
            acc = __builtin_amdgcn_mfma_f32_16x16x32_bf16(afr[ot][0], bfr[0], acc, 0, 0, 0);
            acc = __builtin_amdgcn_mfma_f32_16x16x32_bf16(afr[ot][1], bfr[1], acc, 0, 0, 0);
            u16x4v sv;
            #pragma unroll
            for (int j = 0; j < 4; ++j) {
                float v = acc[j];
                sv[j] = f2us(v);
                psum[ot] += v; psq[ot] += v * v;
            }
            int g = ot * 2 + (lane >> 5);
            *reinterpret_cast<u16x4v*>(
                y3g + (((size_t)b * 16 + g) * NK_ + colme) * 8 + ((lane >> 4) & 1) * 4) = sv;
        }
    }
    float* dst = p3m + ((size_t)(b * 256 + ntile) * 4 + w) * 32;
    #pragma unroll
    for (int ot = 0; ot < 8; ++ot) {
        float s = psum[ot], q = psq[ot];
        #pragma unroll
        for (int off = 16; off > 0; off >>= 1) {
            s += __shfl_down(s, off, 32);
            q += __shfl_down(q, off, 32);
        }
        if ((lane & 31) == 0) {
            int half = lane >> 5;
            dst[ot * 4 + half * 2 + 0] = s;
            dst[ot * 4 + half * 2 + 1] = q;
        }
    }
}

// ---------------- prep4: in-place x3 = bf16(relu(a3*y3 + s3)) on y3g [b][cg=16][col][8c] ----------------
__global__ __launch_bounds__(256) void prep4_kernel(unsigned short* __restrict__ y3g,
    const float* __restrict__ a3, const float* __restrict__ s3)
{
    size_t t = (size_t)blockIdx.x * 256 + threadIdx.x;   // one (b,cg,col) 16B chunk
    int b  = (int)(t / ((size_t)16 * NK_));
    int cg = (int)((t / NK_) & 15);
    const float* ab = a3 + b * 128 + cg * 8;
    const float* sb = s3 + b * 128 + cg * 8;
    u16x8v v = *reinterpret_cast<const u16x8v*>(y3g + t * 8);
    #pragma unroll
    for (int j = 0; j < 8; ++j)
        v[j] = f2us(fmaxf(fmaf(us2f(v[j]), ab[j], sb[j]), 0.f));
    *reinterpret_cast<u16x8v*>(y3g + t * 8) = v;
}

// ---------------- conv4 via MFMA: block = 16n tile, 4 waves x 4 o-passes = all 256 o ----------------
__global__ __launch_bounds__(256) void conv4_mfma_kernel(
    const short* __restrict__ x3g, const short* __restrict__ w4b,
    float* __restrict__ m4, float* __restrict__ part)
{
    int ntile = blockIdx.x, b = blockIdx.z;
    int lane = threadIdx.x & 63, w = threadIdx.x >> 6;
    int colme = ntile * 16 + (lane & 15);
    int cme = (lane >> 4) * 8;

    bf16x8v afr[4][4];
    #pragma unroll
    for (int p = 0; p < 4; ++p) {
        #pragma unroll
        for (int cb = 0; cb < 4; ++cb) {
            size_t aoff = (size_t)(p * 64 + w * 16 + (lane & 15)) * 128 + cb * 32 + cme;
            afr[p][cb] = *reinterpret_cast<const bf16x8v*>(w4b + aoff);
        }
    }

    float am[4][4];
    #pragma unroll
    for (int p = 0; p < 4; ++p)
        #pragma unroll
        for (int j = 0; j < 4; ++j) am[p][j] = -INFINITY;
    float ps[4] = {0.f, 0.f, 0.f, 0.f}, pq[4] = {0.f, 0.f, 0.f, 0.f};

    for (int k = 0; k < K_; ++k) {
        bf16x8v bfr[4];
        #pragma unroll
        for (int cb = 0; cb < 4; ++cb) {
            int cg = cb * 4 + (lane >> 4);
            bfr[cb] = *reinterpret_cast<const bf16x8v*>(
                x3g + (((size_t)b * 16 + cg) * NK_ + (size_t)k * N_ + colme) * 8);
        }
        #pragma unroll
        for (int p = 0; p < 4; ++p) {
            f32x4v acc = { 0.f, 0.f, 0.f, 0.f };
            #pragma unroll
            for (int cb = 0; cb < 4; ++cb)
                acc = __builtin_amdgcn_mfma_f32_16x16x32_bf16(afr[p][cb], bfr[cb], acc, 0, 0, 0);
            #pragma unroll
            for (int j = 0; j < 4; ++j) {
                float v = acc[j];
                am[p][j] = fmaxf(am[p][j], v);
                ps[p] += v; pq[p] += v * v;
            }
        }
    }
    #pragma unroll
    for (int p = 0; p < 4; ++p) {
        #pragma unroll
        for (int j = 0; j < 4; ++j) {
            int o = p * 64 + w * 16 + (lane >> 4) * 4 + j;
            m4[((size_t)b * 256 + o) * N_ + colme] = am[p][j];
        }
        float s = ps[p], q = pq[p];
        #pragma unroll
        for (int off = 32; off > 0; off >>= 1) {
            s += __shfl_down(s, off);
            q += __shfl_down(q, off);
        }
        if (lane == 0) {
            int g = p * 4 + w;
            part[((b * 16 + g) * 2 + 0) * 256 + ntile] = s;
            part[((b * 16 + g) * 2 + 1) * 256 + ntile] = q;
        }
    }
}

// ---------------- GN4 finalize: one WAVE per (b,c), coalesced 256-entry rows ----------------
__global__ __launch_bounds__(256) void finalize4_kernel(const float* __restrict__ part,
    const float* __restrict__ gamma, const float* __restrict__ beta,
    float* __restrict__ ga, float* __restrict__ sh)
{
    int wv = blockIdx.x * 4 + (threadIdx.x >> 6);   // 0..1023 = b*256 + c
    int lane = threadIdx.x & 63;
    int b = wv >> 8, c = wv & 255;
    int g = c >> 4;
    float sum = 0.f, sq = 0.f;
    for (int nt = lane; nt < 256; nt += 64) {
        sum += part[((b * 16 + g) * 2 + 0) * 256 + nt];
        sq  += part[((b * 16 + g) * 2 + 1) * 256 + nt];
    }
    #pragma unroll
    for (int off = 32; off > 0; off >>= 1) {
        sum += __shfl_down(sum, off);
        sq  += __shfl_down(sq, off);
    }
    if (lane == 0) {
        float cnt = 16.f * (float)NK_;
        float mean = sum / cnt;
        float var = fmaxf(sq / cnt - mean * mean, 0.f);
        float sc = gamma[c] * rsqrtf(var + EPS_);
        ga[wv] = sc;
        sh[wv] = beta[c] - mean * sc;
    }
}

// ---------------- final: out = relu(a*max_k + s)  (valid since a>0) ----------------
__global__ __launch_bounds__(256) void apply_kernel(const float* __restrict__ m4,
    const float* __restrict__ ga, const float* __restrict__ sh, float* __restrict__ out)
{
    int t = blockIdx.x * 256 + threadIdx.x;   // b*256*N + c*N + n
    int bc = t >> 12;
    out[t] = fmaxf(fmaf(m4[t], ga[bc], sh[bc]), 0.f);
}

extern "C" void kernel_launch(void* const* d_in, const int* in_sizes, int n_in,
                              void* d_out, int out_size, void* d_ws, size_t ws_size,
                              hipStream_t stream)
{
    const float* pts = (const float*)d_in[0];
    const float* W1 = (const float*)d_in[1];
    const float* g1 = (const float*)d_in[2];
    const float* bt1 = (const float*)d_in[3];
    const float* W2 = (const float*)d_in[4];
    const float* g2 = (const float*)d_in[5];
    const float* bt2 = (const float*)d_in[6];
    const float* W3 = (const float*)d_in[7];
    const float* g3 = (const float*)d_in[8];
    const float* bt3 = (const float*)d_in[9];
    const float* W4 = (const float*)d_in[10];
    const float* g4 = (const float*)d_in[11];
    const float* bt4 = (const float*)d_in[12];
    float* out = (float*)d_out;

    char* ws = (char*)d_ws;
    size_t off = 0;
    auto alloc = [&](size_t bytes) -> void* {
        void* p = ws + off;
        off = (off + bytes + 255) & ~(size_t)255;
        return p;
    };
    int*   idx  = (int*)  alloc((size_t)B_ * NK_ * 4);           // 1.3 MB
    float* x0   = (float*)alloc((size_t)B_ * 13 * NK_ * 4);      // 17 MB
    unsigned short* y2g = (unsigned short*)alloc((size_t)B_ * 8 * NK_ * 8 * 2);   // 42 MB
    unsigned short* y3g = (unsigned short*)alloc((size_t)B_ * 16 * NK_ * 8 * 2);  // 84 MB
    unsigned short* y1g = y3g;   // ALIAS: y1g (42 MB) lives in y3g's buffer; dead before stage3 writes
    float* m4   = (float*)alloc((size_t)B_ * 256 * N_ * 4);      // 16.8 MB
    bf16*  w2b  = (bf16*) alloc(64 * 64 * 2);                    // 8 KB
    bf16*  w3b  = (bf16*) alloc(128 * 64 * 2);                   // 16 KB
    bf16*  w4b  = (bf16*) alloc(256 * 128 * 2);                  // 64 KB
    float* p1   = (float*)alloc((size_t)B_ * NBLK_ * 32 * 4);    // 164 KB
    float* p2m  = (float*)alloc((size_t)B_ * 1024 * 32 * 4);     // 0.5 MB
    float* p3m  = (float*)alloc((size_t)B_ * 1024 * 32 * 4);     // 0.5 MB
    float* part4= (float*)alloc(4 * 16 * 2 * 256 * 4);           // 128 KB
    float* a1 = (float*)alloc(B_ * 64 * 4);
    float* s1 = (float*)alloc(B_ * 64 * 4);
    float* a2 = (float*)alloc(B_ * 64 * 4);
    float* s2 = (float*)alloc(B_ * 64 * 4);
    float* a3 = (float*)alloc(B_ * 128 * 4);
    float* s3 = (float*)alloc(B_ * 128 * 4);
    float* a4 = (float*)alloc(B_ * 256 * 4);
    float* s4 = (float*)alloc(B_ * 256 * 4);
    (void)ws_size; (void)in_sizes; (void)n_in; (void)out_size;

    knn_kernel<<<(B_ * N_) / 4, 256, 0, stream>>>(pts, idx);
    wcast_kernel<<<16, 256, 0, stream>>>(W2, w2b, 64 * 64);
    wcast_kernel<<<32, 256, 0, stream>>>(W3, w3b, 128 * 64);
    wcast_kernel<<<128, 256, 0, stream>>>(W4, w4b, 256 * 128);
    feature_kernel<<<(B_ * NK_) / 256, 256, 0, stream>>>(pts, idx, x0);

    stage1_kernel<<<dim3(NBLK_, B_), 256, 0, stream>>>(x0, W1, y1g, p1);
    finalize_kernel<64><<<64, 256, 0, stream>>>(p1, g1, bt1, a1, s1);

    prep64_kernel<<<(int)(((size_t)B_ * 8 * NK_) / 256), 256, 0, stream>>>(y1g, a1, s1);
    stage2_mfma_kernel<<<dim3(N_ / 16, 1, B_), 256, 0, stream>>>((const short*)y1g, (const short*)w2b, y2g, p2m);
    finalizeM_kernel<64><<<64, 256, 0, stream>>>(p2m, g2, bt2, a2, s2);

    prep64_kernel<<<(int)(((size_t)B_ * 8 * NK_) / 256), 256, 0, stream>>>(y2g, a2, s2);
    stage3_mfma_kernel<<<dim3(N_ / 16, 1, B_), 256, 0, stream>>>((const short*)y2g, (const short*)w3b, y3g, p3m);
    finalizeM_kernel<128><<<128, 256, 0, stream>>>(p3m, g3, bt3, a3, s3);

    prep4_kernel<<<(int)(((size_t)B_ * 16 * NK_) / 256), 256, 0, stream>>>(y3g, a3, s3);
    conv4_mfma_kernel<<<dim3(N_ / 16, 1, B_), 256, 0, stream>>>((const short*)y3g, (const short*)w4b, m4, part4);
    finalize4_kernel<<<256, 256, 0, stream>>>(part4, g4, bt4, a4, s4);

    apply_kernel<<<(B_ * 256 * N_) / 256, 256, 0, stream>>>(m4, a4, s4, out);
}

// Round 24
// 347.358 us; speedup vs baseline: 1.3300x; 1.2957x over previous
//
#include <hip/hip_runtime.h>
#include <hip/hip_bf16.h>
#include <math.h>

#define B_ 4
#define N_ 4096
#define K_ 20
#define NK_ (N_*K_)   // 81920
#define G_ 16
#define EPS_ 1e-5f
#define NBLK_ (NK_/256)   // 320 column-blocks per batch

typedef __hip_bfloat16 bf16;
typedef short bf16x8v __attribute__((ext_vector_type(8)));
typedef unsigned short u16x8v __attribute__((ext_vector_type(8)));
typedef unsigned short u16x4v __attribute__((ext_vector_type(4)));
typedef float f32x4v __attribute__((ext_vector_type(4)));

__device__ inline float b2f(bf16 v) { return __bfloat162float(v); }
__device__ inline bf16  f2b(float v){ return __float2bfloat16(v); }
__device__ inline float us2f(unsigned short u){ unsigned int i = ((unsigned)u) << 16; float f; __builtin_memcpy(&f, &i, 4); return f; }
__device__ inline unsigned short f2us(float f){ bf16 h = __float2bfloat16(f); unsigned short u; __builtin_memcpy(&u, &h, 2); return u; }

template<int CTRL>
__device__ inline float dppmax_step(float v)
{
    int i; __builtin_memcpy(&i, &v, 4);
    int m = __builtin_amdgcn_update_dpp((int)0xFF800000, i, CTRL, 0xF, 0xF, false);
    float f; __builtin_memcpy(&f, &m, 4);
    return fmaxf(v, f);
}

// ---------------- kNN: one WAVE per (b,i); two-level cache + DPP (r21 optimum, reverted) ----------------
// pd arithmetic bit-exact np (no FMA, sequential adds) — LOAD-BEARING, do not change.
// r22 lesson: VGPR>104 halves occupancy. r23 lesson: waves_per_eu(5) forces VGPR=48 -> pd[] spills
// (227MB fetch / 453MB write of scratch traffic). This kernel is pinned at VGPR=104; leave it.
__global__ __launch_bounds__(256)
void knn_kernel(const float* __restrict__ pts, int* __restrict__ idx)
{
    int wid  = (blockIdx.x << 2) | (threadIdx.x >> 6);   // global wave id = b*N + i
    int lane = threadIdx.x & 63;
    int b = wid >> 12, i = wid & (N_ - 1);
    const float* pb = pts + (size_t)b * 6 * N_;
    float xi = pb[i], yi = pb[N_ + i], zi = pb[2 * N_ + i];
    float xxi = __fadd_rn(__fadd_rn(__fmul_rn(xi, xi), __fmul_rn(yi, yi)), __fmul_rn(zi, zi));
    float nxxi = -xxi;

    float pd[64];                    // candidate j = c*64 + lane (statically indexed only)
    #pragma unroll
    for (int c = 0; c < 64; ++c) {
        int j = c * 64 + lane;
        float xj = pb[j], yj = pb[N_ + j], zj = pb[2 * N_ + j];
        float xxj = __fadd_rn(__fadd_rn(__fmul_rn(xj, xj), __fmul_rn(yj, yj)), __fmul_rn(zj, zj));
        float px = __fmul_rn(xi, xj);
        float py = __fmul_rn(yi, yj);
        float pz = __fmul_rn(zi, zj);
        float dot = __fadd_rn(__fadd_rn(px, py), pz);   // NO FMA — matches np
        float inner = __fmul_rn(-2.0f, dot);
        pd[c] = __fsub_rn(__fsub_rn(nxxi, inner), xxj);
    }

    // rank 0 = self: pd[i,i] = +0 exactly is the strict max; emit and retire
    {
        int slot = __builtin_amdgcn_readfirstlane(i >> 6);
        int ln   = __builtin_amdgcn_readfirstlane(i & 63);
        bool me = (lane == ln);
        #pragma unroll
        for (int c = 0; c < 64; ++c)
            if (c == slot) pd[c] = me ? -INFINITY : pd[c];
        if (lane == 0) idx[(size_t)b * NK_ + i] = i;
    }

    float gmax[8];
    #pragma unroll
    for (int g = 0; g < 8; ++g) {
        float m01 = fmaxf(pd[g * 8 + 0], pd[g * 8 + 1]);
        float m23 = fmaxf(pd[g * 8 + 2], pd[g * 8 + 3]);
        float m45 = fmaxf(pd[g * 8 + 4], pd[g * 8 + 5]);
        float m67 = fmaxf(pd[g * 8 + 6], pd[g * 8 + 7]);
        gmax[g] = fmaxf(fmaxf(m01, m23), fmaxf(m45, m67));
    }

    for (int it = 1; it < K_; ++it) {
        float a01 = fmaxf(gmax[0], gmax[1]);
        float a23 = fmaxf(gmax[2], gmax[3]);
        float a45 = fmaxf(gmax[4], gmax[5]);
        float a67 = fmaxf(gmax[6], gmax[7]);
        float vb = fmaxf(fmaxf(a01, a23), fmaxf(a45, a67));

        // wave max via DPP cascade (all VALU; lane 63 ends with global max)
        float r = vb;
        r = dppmax_step<0x111>(r);   // row_shr:1
        r = dppmax_step<0x112>(r);   // row_shr:2
        r = dppmax_step<0x114>(r);   // row_shr:4
        r = dppmax_step<0x118>(r);   // row_shr:8
        r = dppmax_step<0x142>(r);   // row_bcast15
        r = dppmax_step<0x143>(r);   // row_bcast31
        int wvi = __builtin_amdgcn_readlane(__float_as_int(r), 63);
        float wv = __int_as_float(wvi);                 // wave-uniform max value

        unsigned long long mk = __ballot(vb == wv);
        int wl = 63 - __builtin_clzll(mk);              // winner lane (uniform)

        int gsel = 0;
        #pragma unroll
        for (int g = 0; g < 8; ++g)
            if (gmax[g] == wv) gsel = g;
        int gw = __builtin_amdgcn_readlane(gsel, wl);

        int usel = 0;
        #pragma unroll
        for (int g = 0; g < 8; ++g)
            if (g == gw) {                               // gw uniform -> static branch
                #pragma unroll
                for (int u = 0; u < 8; ++u)
                    if (pd[g * 8 + u] == wv) usel = u;
            }
        int uw = __builtin_amdgcn_readlane(usel, wl);

        int bj = (gw * 8 + uw) * 64 + wl;
        if (lane == 0) idx[(size_t)b * NK_ + it * N_ + i] = bj;

        bool me = (lane == wl);
        #pragma unroll
        for (int g = 0; g < 8; ++g)
            if (g == gw) {
                #pragma unroll
                for (int u = 0; u < 8; ++u)
                    if (u == uw) pd[g * 8 + u] = me ? -INFINITY : pd[g * 8 + u];
                float m01 = fmaxf(pd[g * 8 + 0], pd[g * 8 + 1]);
                float m23 = fmaxf(pd[g * 8 + 2], pd[g * 8 + 3]);
                float m45 = fmaxf(pd[g * 8 + 4], pd[g * 8 + 5]);
                float m67 = fmaxf(pd[g * 8 + 6], pd[g * 8 + 7]);
                gmax[g] = fmaxf(fmaxf(m01, m23), fmaxf(m45, m67));
            }
    }
}

// ---------------- angle: "x<0" quadrant predicate — LOAD-BEARING (round 10) ----------------
__device__ inline float angle3(float ax, float ay, float az, float bx, float by, float bz)
{
    float cx = __fsub_rn(__fmul_rn(ay, bz), __fmul_rn(az, by));
    float cy = __fsub_rn(__fmul_rn(az, bx), __fmul_rn(ax, bz));
    float cz = __fsub_rn(__fmul_rn(ax, by), __fmul_rn(ay, bx));
    float cn = sqrtf(__fadd_rn(__fadd_rn(__fmul_rn(cx, cx), __fmul_rn(cy, cy)), __fmul_rn(cz, cz)));
    float d  = __fadd_rn(__fadd_rn(__fmul_rn(ax, bx), __fmul_rn(ay, by)), __fmul_rn(az, bz));
    if (cn == 0.0f)
        return (d < 0.0f) ? 3.14159274101257324e+00f : 0.0f;   // -0 -> 0
    return atan2f(cn, d);
}

__global__ __launch_bounds__(256) void feature_kernel(const float* __restrict__ pts,
                                                      const int* __restrict__ idx,
                                                      float* __restrict__ x0)
{
    int t = blockIdx.x * 256 + threadIdx.x;           // [0, B*NK)
    int col = t % NK_;
    int b = t / NK_;
    int n = col & (N_ - 1);
    int j = idx[t];
    const float* pb = pts + (size_t)b * 6 * N_;
    float cx = pb[n],            cy = pb[N_ + n],     cz = pb[2 * N_ + n];
    float gx = pb[j],            gy = pb[N_ + j],     gz = pb[2 * N_ + j];
    float rx = pb[3 * N_ + n],   ry = pb[4 * N_ + n], rz = pb[5 * N_ + n];
    float ix = pb[3 * N_ + j],   iy = pb[4 * N_ + j], iz = pb[5 * N_ + j];
    float lx = __fsub_rn(gx, cx), ly = __fsub_rn(gy, cy), lz = __fsub_rn(gz, cz);

    float f9  = angle3(rx, ry, rz, lx, ly, lz);
    float f10 = angle3(ix, iy, iz, lx, ly, lz);
    float f11 = angle3(rx, ry, rz, ix, iy, iz);
    float f12 = sqrtf(__fadd_rn(__fadd_rn(__fmul_rn(lx, lx), __fmul_rn(ly, ly)), __fmul_rn(lz, lz)));

    float* xp = x0 + (size_t)b * 13 * NK_ + col;
    xp[0  * (size_t)NK_] = gx;
    xp[1  * (size_t)NK_] = gy;
    xp[2  * (size_t)NK_] = gz;
    xp[3  * (size_t)NK_] = cx;
    xp[4  * (size_t)NK_] = cy;
    xp[5  * (size_t)NK_] = cz;
    xp[6  * (size_t)NK_] = lx;
    xp[7  * (size_t)NK_] = ly;
    xp[8  * (size_t)NK_] = lz;
    xp[9  * (size_t)NK_] = f9;
    xp[10 * (size_t)NK_] = f10;
    xp[11 * (size_t)NK_] = f11;
    xp[12 * (size_t)NK_] = f12;
}

// ---------------- deterministic block reduction: 16 sums + 16 sumsqs -> 32 partials ----------------
__device__ inline void block_reduce_write(const float gsum[16], const float gsq[16], float* __restrict__ dst)
{
    __shared__ float red[4][32];
    int t = threadIdx.x, lane = t & 63, w = t >> 6;
    #pragma unroll
    for (int r = 0; r < 16; ++r) {
        float v = gsum[r];
        #pragma unroll
        for (int off = 32; off > 0; off >>= 1) v += __shfl_down(v, off);
        if (lane == 0) red[w][r] = v;
        float q = gsq[r];
        #pragma unroll
        for (int off = 32; off > 0; off >>= 1) q += __shfl_down(q, off);
        if (lane == 0) red[w][16 + r] = q;
    }
    __syncthreads();
    if (t < 32) dst[t] = red[0][t] + red[1][t] + red[2][t] + red[3][t];
}

// ---------------- stage1: conv1 -> y1g raw bf16 [b][og=8][col][8] + GN1 partial stats ----------------
__global__ __launch_bounds__(256) void stage1_kernel(const float* __restrict__ x0,
    const float* __restrict__ W1, unsigned short* __restrict__ y1g, float* __restrict__ p1)
{
    int b = blockIdx.y;
    int col = blockIdx.x * 256 + threadIdx.x;
    const float* xb = x0 + (size_t)b * 13 * NK_ + col;
    float xr[13];
    #pragma unroll
    for (int c = 0; c < 13; ++c) xr[c] = xb[(size_t)c * NK_];
    float gsum[16], gsq[16];
    #pragma unroll
    for (int r = 0; r < 16; ++r) { gsum[r] = 0.f; gsq[r] = 0.f; }
    #pragma unroll
    for (int og = 0; og < 8; ++og) {
        u16x8v row;
        #pragma unroll
        for (int oi = 0; oi < 8; ++oi) {
            int o = og * 8 + oi;
            float acc = 0.f;
            #pragma unroll
            for (int c = 0; c < 13; ++c) acc = fmaf(W1[o * 13 + c], xr[c], acc);
            row[oi] = f2us(acc);
            gsum[og * 2 + (oi >> 2)] += acc;           // GN group o>>2, compile-time index
            gsq[og * 2 + (oi >> 2)] += acc * acc;      // stats on pre-rounding fp32
        }
        *reinterpret_cast<u16x8v*>(y1g + (((size_t)b * 8 + og) * NK_ + col) * 8) = row;
    }
    block_reduce_write(gsum, gsq, p1 + ((size_t)b * NBLK_ + blockIdx.x) * 32);
}

// ---------------- fold GN into per-(b,c) scale/shift from block partials: one WAVE per (b,c) ----------------
template<int COUT>
__global__ __launch_bounds__(256) void finalize_kernel(const float* __restrict__ part,
    const float* __restrict__ gamma, const float* __restrict__ beta,
    float* __restrict__ ga, float* __restrict__ sh)
{
    int wv = blockIdx.x * 4 + (threadIdx.x >> 6);   // wave id = b*COUT + c
    int lane = threadIdx.x & 63;
    int b = wv / COUT, c = wv % COUT;
    int g = c / (COUT / G_);
    float sum = 0.f, sq = 0.f;
    for (int blk = lane; blk < NBLK_; blk += 64) {
        const float* d = part + ((size_t)b * NBLK_ + blk) * 32;
        sum += d[g]; sq += d[16 + g];
    }
    #pragma unroll
    for (int off = 32; off > 0; off >>= 1) {
        sum += __shfl_down(sum, off);
        sq  += __shfl_down(sq, off);
    }
    if (lane == 0) {
        float cnt = (float)(COUT / G_) * (float)NK_;
        float mean = sum / cnt;
        float var = fmaxf(sq / cnt - mean * mean, 0.f);
        float sc = gamma[c] * rsqrtf(var + EPS_);
        ga[wv] = sc;
        sh[wv] = beta[c] - mean * sc;
    }
}

// ---------------- finalizeM: GN fold from MFMA partials [b][1024 sets][32] (e = 2g) ----------------
template<int COUT>
__global__ __launch_bounds__(256) void finalizeM_kernel(const float* __restrict__ pm,
    const float* __restrict__ gamma, const float* __restrict__ beta,
    float* __restrict__ ga, float* __restrict__ sh)
{
    int wv = blockIdx.x * 4 + (threadIdx.x >> 6);   // wave id = b*COUT + c
    int lane = threadIdx.x & 63;
    int b = wv / COUT, c = wv % COUT;
    int g = c / (COUT / G_);
    int e = g * 2;
    float sum = 0.f, sq = 0.f;
    for (int s = lane; s < 1024; s += 64) {
        const float* d = pm + ((size_t)(b * 1024 + s)) * 32;
        sum += d[e]; sq += d[e + 1];
    }
    #pragma unroll
    for (int off = 32; off > 0; off >>= 1) {
        sum += __shfl_down(sum, off);
        sq  += __shfl_down(sq, off);
    }
    if (lane == 0) {
        float cnt = (float)(COUT / G_) * (float)NK_;
        float mean = sum / cnt;
        float var = fmaxf(sq / cnt - mean * mean, 0.f);
        float sc = gamma[c] * rsqrtf(var + EPS_);
        ga[wv] = sc;
        sh[wv] = beta[c] - mean * sc;
    }
}

// ---------------- weight -> bf16 casts ----------------
__global__ __launch_bounds__(256) void wcast_kernel(const float* __restrict__ W, bf16* __restrict__ Wb, int n)
{
    int t = blockIdx.x * 256 + threadIdx.x;
    if (t < n) Wb[t] = f2b(W[t]);
}

// ---------------- prep64: in-place x = bf16(relu(a*y + s)) on 64-ch grouped [b][cg=8][col][8c] ----------------
__global__ __launch_bounds__(256) void prep64_kernel(unsigned short* __restrict__ yg,
    const float* __restrict__ a, const float* __restrict__ s)
{
    size_t t = (size_t)blockIdx.x * 256 + threadIdx.x;   // one (b,cg,col) 16B chunk
    int b  = (int)(t / ((size_t)8 * NK_));
    int cg = (int)((t / NK_) & 7);
    const float* ab = a + b * 64 + cg * 8;
    const float* sb = s + b * 64 + cg * 8;
    u16x8v v = *reinterpret_cast<const u16x8v*>(yg + t * 8);
    #pragma unroll
    for (int j = 0; j < 8; ++j)
        v[j] = f2us(fmaxf(fmaf(us2f(v[j]), ab[j], sb[j]), 0.f));
    *reinterpret_cast<u16x8v*>(yg + t * 8) = v;
}

// ---------------- stage2 via MFMA: y2 = W2(64x64) x x1 -> y2g grouped + GN2 partials ----------------
__global__ __launch_bounds__(256) void stage2_mfma_kernel(
    const short* __restrict__ x1g, const short* __restrict__ w2b,
    unsigned short* __restrict__ y2g, float* __restrict__ p2m)
{
    int ntile = blockIdx.x, b = blockIdx.z;
    int lane = threadIdx.x & 63, w = threadIdx.x >> 6;
    int colbase = ntile * 16 + (lane & 15);
    int cme = (lane >> 4) * 8;

    bf16x8v afr[4][2];
    #pragma unroll
    for (int ot = 0; ot < 4; ++ot)
        #pragma unroll
        for (int kb = 0; kb < 2; ++kb)
            afr[ot][kb] = *reinterpret_cast<const bf16x8v*>(
                w2b + (size_t)(ot * 16 + (lane & 15)) * 64 + kb * 32 + cme);

    float psum[4], psq[4];
    #pragma unroll
    for (int ot = 0; ot < 4; ++ot) { psum[ot] = 0.f; psq[ot] = 0.f; }

    for (int kk = 0; kk < 5; ++kk) {
        int k = kk * 4 + w;
        int colme = k * N_ + colbase;
        bf16x8v bfr[2];
        #pragma unroll
        for (int kb = 0; kb < 2; ++kb) {
            int cg = kb * 4 + (lane >> 4);
            bfr[kb] = *reinterpret_cast<const bf16x8v*>(
                x1g + (((size_t)b * 8 + cg) * NK_ + colme) * 8);
        }
        #pragma unroll
        for (int ot = 0; ot < 4; ++ot) {
            f32x4v acc = { 0.f, 0.f, 0.f, 0.f };
            acc = __builtin_amdgcn_mfma_f32_16x16x32_bf16(afr[ot][0], bfr[0], acc, 0, 0, 0);
            acc = __builtin_amdgcn_mfma_f32_16x16x32_bf16(afr[ot][1], bfr[1], acc, 0, 0, 0);
            u16x4v sv;
            #pragma unroll
            for (int j = 0; j < 4; ++j) {
                float v = acc[j];
                sv[j] = f2us(v);
                psum[ot] += v; psq[ot] += v * v;
            }
            int cgo = ot * 2 + (lane >> 5);           // output c-group (8ch)
            *reinterpret_cast<u16x4v*>(
                y2g + (((size_t)b * 8 + cgo) * NK_ + colme) * 8 + ((lane >> 4) & 1) * 4) = sv;
        }
    }
    float* dst = p2m + ((size_t)(b * 256 + ntile) * 4 + w) * 32;
    int qq = lane >> 4;
    #pragma unroll
    for (int ot = 0; ot < 4; ++ot) {
        float s = psum[ot], q = psq[ot];
        #pragma unroll
        for (int off = 8; off > 0; off >>= 1) {
            s += __shfl_down(s, off, 16);
            q += __shfl_down(q, off, 16);
        }
        if ((lane & 15) == 0) {
            dst[(ot * 4 + qq) * 2 + 0] = s;
            dst[(ot * 4 + qq) * 2 + 1] = q;
        }
    }
}

// ---------------- stage3 via MFMA: y3 = W3(128x64) x x2 -> y3g grouped + GN3 partials ----------------
__global__ __launch_bounds__(256) void stage3_mfma_kernel(
    const short* __restrict__ x2g, const short* __restrict__ w3b,
    unsigned short* __restrict__ y3g, float* __restrict__ p3m)
{
    int ntile = blockIdx.x, b = blockIdx.z;
    int lane = threadIdx.x & 63, w = threadIdx.x >> 6;
    int colbase = ntile * 16 + (lane & 15);
    int cme = (lane >> 4) * 8;

    bf16x8v afr[8][2];
    #pragma unroll
    for (int ot = 0; ot < 8; ++ot)
        #pragma unroll
        for (int kb = 0; kb < 2; ++kb)
            afr[ot][kb] = *reinterpret_cast<const bf16x8v*>(
                w3b + (size_t)(ot * 16 + (lane & 15)) * 64 + kb * 32 + cme);

    float psum[8], psq[8];
    #pragma unroll
    for (int ot = 0; ot < 8; ++ot) { psum[ot] = 0.f; psq[ot] = 0.f; }

    for (int kk = 0; kk < 5; ++kk) {
        int k = kk * 4 + w;
        int colme = k * N_ + colbase;
        bf16x8v bfr[2];
        #pragma unroll
        for (int kb = 0; kb < 2; ++kb) {
            int cg = kb * 4 + (lane >> 4);
            bfr[kb] = *reinterpret_cast<const bf16x8v*>(
                x2g + (((size_t)b * 8 + cg) * NK_ + colme) * 8);
        }
        #pragma unroll
        for (int ot = 0; ot < 8; ++ot) {
            f32x4v acc = { 0.f, 0.f, 0.f, 0.f };
            acc = __builtin_amdgcn_mfma_f32_16x16x32_bf16(afr[ot][0], bfr[0], acc, 0, 0, 0);
            acc = __builtin_amdgcn_mfma_f32_16x16x32_bf16(afr[ot][1], bfr[1], acc, 0, 0, 0);
            u16x4v sv;
            #pragma unroll
            for (int j = 0; j < 4; ++j) {
                float v = acc[j];
                sv[j] = f2us(v);
                psum[ot] += v; psq[ot] += v * v;
            }
            int g = ot * 2 + (lane >> 5);
            *reinterpret_cast<u16x4v*>(
                y3g + (((size_t)b * 16 + g) * NK_ + colme) * 8 + ((lane >> 4) & 1) * 4) = sv;
        }
    }
    float* dst = p3m + ((size_t)(b * 256 + ntile) * 4 + w) * 32;
    #pragma unroll
    for (int ot = 0; ot < 8; ++ot) {
        float s = psum[ot], q = psq[ot];
        #pragma unroll
        for (int off = 16; off > 0; off >>= 1) {
            s += __shfl_down(s, off, 32);
            q += __shfl_down(q, off, 32);
        }
        if ((lane & 31) == 0) {
            int half = lane >> 5;
            dst[ot * 4 + half * 2 + 0] = s;
            dst[ot * 4 + half * 2 + 1] = q;
        }
    }
}

// ---------------- prep4: in-place x3 = bf16(relu(a3*y3 + s3)) on y3g [b][cg=16][col][8c] ----------------
__global__ __launch_bounds__(256) void prep4_kernel(unsigned short* __restrict__ y3g,
    const float* __restrict__ a3, const float* __restrict__ s3)
{
    size_t t = (size_t)blockIdx.x * 256 + threadIdx.x;   // one (b,cg,col) 16B chunk
    int b  = (int)(t / ((size_t)16 * NK_));
    int cg = (int)((t / NK_) & 15);
    const float* ab = a3 + b * 128 + cg * 8;
    const float* sb = s3 + b * 128 + cg * 8;
    u16x8v v = *reinterpret_cast<const u16x8v*>(y3g + t * 8);
    #pragma unroll
    for (int j = 0; j < 8; ++j)
        v[j] = f2us(fmaxf(fmaf(us2f(v[j]), ab[j], sb[j]), 0.f));
    *reinterpret_cast<u16x8v*>(y3g + t * 8) = v;
}

// ---------------- conv4 via MFMA: block = 16n tile, 4 waves x 4 o-passes = all 256 o ----------------
__global__ __launch_bounds__(256) void conv4_mfma_kernel(
    const short* __restrict__ x3g, const short* __restrict__ w4b,
    float* __restrict__ m4, float* __restrict__ part)
{
    int ntile = blockIdx.x, b = blockIdx.z;
    int lane = threadIdx.x & 63, w = threadIdx.x >> 6;
    int colme = ntile * 16 + (lane & 15);
    int cme = (lane >> 4) * 8;

    bf16x8v afr[4][4];
    #pragma unroll
    for (int p = 0; p < 4; ++p) {
        #pragma unroll
        for (int cb = 0; cb < 4; ++cb) {
            size_t aoff = (size_t)(p * 64 + w * 16 + (lane & 15)) * 128 + cb * 32 + cme;
            afr[p][cb] = *reinterpret_cast<const bf16x8v*>(w4b + aoff);
        }
    }

    float am[4][4];
    #pragma unroll
    for (int p = 0; p < 4; ++p)
        #pragma unroll
        for (int j = 0; j < 4; ++j) am[p][j] = -INFINITY;
    float ps[4] = {0.f, 0.f, 0.f, 0.f}, pq[4] = {0.f, 0.f, 0.f, 0.f};

    for (int k = 0; k < K_; ++k) {
        bf16x8v bfr[4];
        #pragma unroll
        for (int cb = 0; cb < 4; ++cb) {
            int cg = cb * 4 + (lane >> 4);
            bfr[cb] = *reinterpret_cast<const bf16x8v*>(
                x3g + (((size_t)b * 16 + cg) * NK_ + (size_t)k * N_ + colme) * 8);
        }
        #pragma unroll
        for (int p = 0; p < 4; ++p) {
            f32x4v acc = { 0.f, 0.f, 0.f, 0.f };
            #pragma unroll
            for (int cb = 0; cb < 4; ++cb)
                acc = __builtin_amdgcn_mfma_f32_16x16x32_bf16(afr[p][cb], bfr[cb], acc, 0, 0, 0);
            #pragma unroll
            for (int j = 0; j < 4; ++j) {
                float v = acc[j];
                am[p][j] = fmaxf(am[p][j], v);
                ps[p] += v; pq[p] += v * v;
            }
        }
    }
    #pragma unroll
    for (int p = 0; p < 4; ++p) {
        #pragma unroll
        for (int j = 0; j < 4; ++j) {
            int o = p * 64 + w * 16 + (lane >> 4) * 4 + j;
            m4[((size_t)b * 256 + o) * N_ + colme] = am[p][j];
        }
        float s = ps[p], q = pq[p];
        #pragma unroll
        for (int off = 32; off > 0; off >>= 1) {
            s += __shfl_down(s, off);
            q += __shfl_down(q, off);
        }
        if (lane == 0) {
            int g = p * 4 + w;
            part[((b * 16 + g) * 2 + 0) * 256 + ntile] = s;
            part[((b * 16 + g) * 2 + 1) * 256 + ntile] = q;
        }
    }
}

// ---------------- GN4 finalize: one WAVE per (b,c), coalesced 256-entry rows ----------------
__global__ __launch_bounds__(256) void finalize4_kernel(const float* __restrict__ part,
    const float* __restrict__ gamma, const float* __restrict__ beta,
    float* __restrict__ ga, float* __restrict__ sh)
{
    int wv = blockIdx.x * 4 + (threadIdx.x >> 6);   // 0..1023 = b*256 + c
    int lane = threadIdx.x & 63;
    int b = wv >> 8, c = wv & 255;
    int g = c >> 4;
    float sum = 0.f, sq = 0.f;
    for (int nt = lane; nt < 256; nt += 64) {
        sum += part[((b * 16 + g) * 2 + 0) * 256 + nt];
        sq  += part[((b * 16 + g) * 2 + 1) * 256 + nt];
    }
    #pragma unroll
    for (int off = 32; off > 0; off >>= 1) {
        sum += __shfl_down(sum, off);
        sq  += __shfl_down(sq, off);
    }
    if (lane == 0) {
        float cnt = 16.f * (float)NK_;
        float mean = sum / cnt;
        float var = fmaxf(sq / cnt - mean * mean, 0.f);
        float sc = gamma[c] * rsqrtf(var + EPS_);
        ga[wv] = sc;
        sh[wv] = beta[c] - mean * sc;
    }
}

// ---------------- final: out = relu(a*max_k + s)  (valid since a>0) ----------------
__global__ __launch_bounds__(256) void apply_kernel(const float* __restrict__ m4,
    const float* __restrict__ ga, const float* __restrict__ sh, float* __restrict__ out)
{
    int t = blockIdx.x * 256 + threadIdx.x;   // b*256*N + c*N + n
    int bc = t >> 12;
    out[t] = fmaxf(fmaf(m4[t], ga[bc], sh[bc]), 0.f);
}

extern "C" void kernel_launch(void* const* d_in, const int* in_sizes, int n_in,
                              void* d_out, int out_size, void* d_ws, size_t ws_size,
                              hipStream_t stream)
{
    const float* pts = (const float*)d_in[0];
    const float* W1 = (const float*)d_in[1];
    const float* g1 = (const float*)d_in[2];
    const float* bt1 = (const float*)d_in[3];
    const float* W2 = (const float*)d_in[4];
    const float* g2 = (const float*)d_in[5];
    const float* bt2 = (const float*)d_in[6];
    const float* W3 = (const float*)d_in[7];
    const float* g3 = (const float*)d_in[8];
    const float* bt3 = (const float*)d_in[9];
    const float* W4 = (const float*)d_in[10];
    const float* g4 = (const float*)d_in[11];
    const float* bt4 = (const float*)d_in[12];
    float* out = (float*)d_out;

    char* ws = (char*)d_ws;
    size_t off = 0;
    auto alloc = [&](size_t bytes) -> void* {
        void* p = ws + off;
        off = (off + bytes + 255) & ~(size_t)255;
        return p;
    };
    int*   idx  = (int*)  alloc((size_t)B_ * NK_ * 4);           // 1.3 MB
    float* x0   = (float*)alloc((size_t)B_ * 13 * NK_ * 4);      // 17 MB
    unsigned short* y2g = (unsigned short*)alloc((size_t)B_ * 8 * NK_ * 8 * 2);   // 42 MB
    unsigned short* y3g = (unsigned short*)alloc((size_t)B_ * 16 * NK_ * 8 * 2);  // 84 MB
    unsigned short* y1g = y3g;   // ALIAS: y1g (42 MB) lives in y3g's buffer; dead before stage3 writes
    float* m4   = (float*)alloc((size_t)B_ * 256 * N_ * 4);      // 16.8 MB
    bf16*  w2b  = (bf16*) alloc(64 * 64 * 2);                    // 8 KB
    bf16*  w3b  = (bf16*) alloc(128 * 64 * 2);                   // 16 KB
    bf16*  w4b  = (bf16*) alloc(256 * 128 * 2);                  // 64 KB
    float* p1   = (float*)alloc((size_t)B_ * NBLK_ * 32 * 4);    // 164 KB
    float* p2m  = (float*)alloc((size_t)B_ * 1024 * 32 * 4);     // 0.5 MB
    float* p3m  = (float*)alloc((size_t)B_ * 1024 * 32 * 4);     // 0.5 MB
    float* part4= (float*)alloc(4 * 16 * 2 * 256 * 4);           // 128 KB
    float* a1 = (float*)alloc(B_ * 64 * 4);
    float* s1 = (float*)alloc(B_ * 64 * 4);
    float* a2 = (float*)alloc(B_ * 64 * 4);
    float* s2 = (float*)alloc(B_ * 64 * 4);
    float* a3 = (float*)alloc(B_ * 128 * 4);
    float* s3 = (float*)alloc(B_ * 128 * 4);
    float* a4 = (float*)alloc(B_ * 256 * 4);
    float* s4 = (float*)alloc(B_ * 256 * 4);
    (void)ws_size; (void)in_sizes; (void)n_in; (void)out_size;

    knn_kernel<<<(B_ * N_) / 4, 256, 0, stream>>>(pts, idx);
    wcast_kernel<<<16, 256, 0, stream>>>(W2, w2b, 64 * 64);
    wcast_kernel<<<32, 256, 0, stream>>>(W3, w3b, 128 * 64);
    wcast_kernel<<<128, 256, 0, stream>>>(W4, w4b, 256 * 128);
    feature_kernel<<<(B_ * NK_) / 256, 256, 0, stream>>>(pts, idx, x0);

    stage1_kernel<<<dim3(NBLK_, B_), 256, 0, stream>>>(x0, W1, y1g, p1);
    finalize_kernel<64><<<64, 256, 0, stream>>>(p1, g1, bt1, a1, s1);

    prep64_kernel<<<(int)(((size_t)B_ * 8 * NK_) / 256), 256, 0, stream>>>(y1g, a1, s1);
    stage2_mfma_kernel<<<dim3(N_ / 16, 1, B_), 256, 0, stream>>>((const short*)y1g, (const short*)w2b, y2g, p2m);
    finalizeM_kernel<64><<<64, 256, 0, stream>>>(p2m, g2, bt2, a2, s2);

    prep64_kernel<<<(int)(((size_t)B_ * 8 * NK_) / 256), 256, 0, stream>>>(y2g, a2, s2);
    stage3_mfma_kernel<<<dim3(N_ / 16, 1, B_), 256, 0, stream>>>((const short*)y2g, (const short*)w3b, y3g, p3m);
    finalizeM_kernel<128><<<128, 256, 0, stream>>>(p3m, g3, bt3, a3, s3);

    prep4_kernel<<<(int)(((size_t)B_ * 16 * NK_) / 256), 256, 0, stream>>>(y3g, a3, s3);
    conv4_mfma_kernel<<<dim3(N_ / 16, 1, B_), 256, 0, stream>>>((const short*)y3g, (const short*)w4b, m4, part4);
    finalize4_kernel<<<256, 256, 0, stream>>>(part4, g4, bt4, a4, s4);

    apply_kernel<<<(B_ * 256 * N_) / 256, 256, 0, stream>>>(m4, a4, s4, out);
}